// Round 3
// baseline (224.254 us; speedup 1.0000x reference)
//
#include <hip/hip_runtime.h>

#define L 1024
#define CIN 512
#define NH 32
#define DH 64
#define NB 2
#define AF 2048

typedef unsigned short u16;
typedef unsigned int u32;
typedef __attribute__((ext_vector_type(8))) short bfx8;   // 8 bf16 = 4 VGPR (MFMA A/B frag)
typedef __attribute__((ext_vector_type(4))) short bfx4;   // 8B half-frag
typedef __attribute__((ext_vector_type(4))) float fx4;    // MFMA C/D frag

struct __align__(8) us4 { u16 x, y, z, w; };

#define MFMA16 __builtin_amdgcn_mfma_f32_16x16x32_bf16

__device__ inline void gld16(const void* g, void* l) {
    __builtin_amdgcn_global_load_lds(
        (const __attribute__((address_space(1))) u32*)g,
        (__attribute__((address_space(3))) u32*)l, 16, 0, 0);
}

__device__ inline u16 f2b(float f) {
    union { float f; u32 u; } v; v.f = f;
    u32 u = v.u;
    return (u16)((u + 0x7fffu + ((u >> 16) & 1u)) >> 16);
}

// ---------------------------------------------------------------------------
// Elementwise fp32 -> bf16 convert (weights). n4 = element count / 4.
// ---------------------------------------------------------------------------
__global__ __launch_bounds__(256) void convert_f2b4(
    const float* __restrict__ in, u16* __restrict__ out, int n4)
{
    int i = blockIdx.x * 256 + threadIdx.x;
    int stride = gridDim.x * 256;
    for (; i < n4; i += stride) {
        float4 v = ((const float4*)in)[i];
        us4 o = { f2b(v.x), f2b(v.y), f2b(v.z), f2b(v.w) };
        ((us4*)out)[i] = o;
    }
}

// ---------------------------------------------------------------------------
// x [B][CIN][L] fp32 -> xT [B][L][CIN] bf16 (transpose + convert)
// grid (CIN/64, L/64, B), block 256
// ---------------------------------------------------------------------------
__global__ __launch_bounds__(256) void convert_xT(
    const float* __restrict__ x, u16* __restrict__ xT)
{
    const int c0 = blockIdx.x * 64, l0 = blockIdx.y * 64, b = blockIdx.z;
    __shared__ u16 tile[64][68];   // [c][l]
    const int t = threadIdx.x;
    const int tr = t >> 4, tc4 = (t & 15) * 4;
    #pragma unroll
    for (int p = 0; p < 4; ++p) {
        int c = p * 16 + tr;
        float4 v = *(const float4*)(x + ((size_t)(b * CIN + c0 + c)) * L + l0 + tc4);
        tile[c][tc4 + 0] = f2b(v.x); tile[c][tc4 + 1] = f2b(v.y);
        tile[c][tc4 + 2] = f2b(v.z); tile[c][tc4 + 3] = f2b(v.w);
    }
    __syncthreads();
    #pragma unroll
    for (int p = 0; p < 4; ++p) {
        int l = p * 16 + tr;
        us4 o = { tile[tc4 + 0][l], tile[tc4 + 1][l], tile[tc4 + 2][l], tile[tc4 + 3][l] };
        *(us4*)(xT + ((size_t)(b * L + l0 + l)) * CIN + c0 + tc4) = o;
    }
}

// ---------------------------------------------------------------------------
// bf16 transpose: in [B][L][AF] (vT[l][c]) -> out [B][AF][L] (v[c][l])
// grid (AF/64, L/64, B)
// ---------------------------------------------------------------------------
__global__ __launch_bounds__(256) void transpose_b(
    const u16* __restrict__ in, u16* __restrict__ out)
{
    const int c0 = blockIdx.x * 64, l0 = blockIdx.y * 64, b = blockIdx.z;
    __shared__ u16 tile[64][68];   // [l][c]
    const int t = threadIdx.x;
    const int tr = t >> 4, tc4 = (t & 15) * 4;
    #pragma unroll
    for (int p = 0; p < 4; ++p) {
        int l = p * 16 + tr;
        us4 v = *(const us4*)(in + ((size_t)(b * L + l0 + l)) * AF + c0 + tc4);
        tile[l][tc4 + 0] = v.x; tile[l][tc4 + 1] = v.y;
        tile[l][tc4 + 2] = v.z; tile[l][tc4 + 3] = v.w;
    }
    __syncthreads();
    #pragma unroll
    for (int p = 0; p < 4; ++p) {
        int c = p * 16 + tr;
        us4 o = { tile[tc4 + 0][c], tile[tc4 + 1][c], tile[tc4 + 2][c], tile[tc4 + 3][c] };
        *(us4*)(out + ((size_t)(b * AF + c0 + c)) * L + l0 + tc4) = o;
    }
}

// ---------------------------------------------------------------------------
// MFMA GEMM: C[M,N] = A[M,K] * B[K,N] (+bias[M], optional relu)
// A [M,K] bf16 row-major, BT [N,K] bf16 row-major (= B^T).
// CT_OUT=1: store C^T bf16 [N][M] (contiguous us4 stores).
// CT_OUT=0: store C fp32 [M][N].
// NA=3: grid.z = b*3+which, A/bias selected from {A0,A1,A2}; out += which*sWhich.
// 128x128 tile, BK=32, 256 threads (4 waves of 64x64).
// ---------------------------------------------------------------------------
template<int RELU, int CT_OUT, int NA>
__global__ __launch_bounds__(256) void gemm_bt(
    const u16* __restrict__ A0, const u16* __restrict__ A1, const u16* __restrict__ A2,
    const float* __restrict__ bias0, const float* __restrict__ bias1, const float* __restrict__ bias2,
    const u16* __restrict__ BTb, void* __restrict__ Cb,
    int M, int N, int K, size_t sBT, size_t sC, size_t sWhich)
{
    const int z = blockIdx.z;
    const int which = (NA == 3) ? (z % 3) : 0;
    const int b     = (NA == 3) ? (z / 3) : z;
    const u16* __restrict__ A = (which == 0) ? A0 : (which == 1) ? A1 : A2;
    const float* __restrict__ bias = (which == 0) ? bias0 : (which == 1) ? bias1 : bias2;
    const u16* __restrict__ BT = BTb + (size_t)b * sBT;
    const int m0 = blockIdx.y * 128, n0 = blockIdx.x * 128;

    __shared__ u16 lA[128 * 32];
    __shared__ u16 lB[128 * 32];

    const int t = threadIdx.x, lane = t & 63, wave = t >> 6;
    const int wm = (wave >> 1) * 64, wn = (wave & 1) * 64;
    const int rl = lane & 15, kh = lane >> 4;

    fx4 acc[4][4];
    #pragma unroll
    for (int i = 0; i < 4; ++i)
        #pragma unroll
        for (int j = 0; j < 4; ++j) acc[i][j] = (fx4){0.f, 0.f, 0.f, 0.f};

    // staging: 512 16B-slots; slot s -> row s>>2, chunk-pos s&3; src chunk = pos ^ ((r>>1)&3)
    const int s0 = t, s1 = t + 256;
    const int r0 = s0 >> 2, cs0 = (s0 & 3) ^ ((r0 >> 1) & 3);
    const int r1 = s1 >> 2, cs1 = (s1 & 3) ^ ((r1 >> 1) & 3);
    const u16* gA0 = A  + (size_t)(m0 + r0) * K + cs0 * 8;
    const u16* gA1 = A  + (size_t)(m0 + r1) * K + cs1 * 8;
    const u16* gB0 = BT + (size_t)(n0 + r0) * K + cs0 * 8;
    const u16* gB1 = BT + (size_t)(n0 + r1) * K + cs1 * 8;

    // frag read offsets (ushort idx): row r, k-chunk kh -> r*32 + ((kh ^ ((r>>1)&3))*8)
    int aoff[4], boff[4];
    #pragma unroll
    for (int f = 0; f < 4; ++f) {
        int ra = wm + f * 16 + rl;
        int rb = wn + f * 16 + rl;
        aoff[f] = ra * 32 + ((kh ^ ((ra >> 1) & 3)) * 8);
        boff[f] = rb * 32 + ((kh ^ ((rb >> 1) & 3)) * 8);
    }

    for (int k0 = 0; k0 < K; k0 += 32) {
        __syncthreads();
        gld16(gA0 + k0, lA + s0 * 8);
        gld16(gA1 + k0, lA + s1 * 8);
        gld16(gB0 + k0, lB + s0 * 8);
        gld16(gB1 + k0, lB + s1 * 8);
        __syncthreads();
        bfx8 af[4], bf[4];
        #pragma unroll
        for (int f = 0; f < 4; ++f) af[f] = *(const bfx8*)&lA[aoff[f]];
        #pragma unroll
        for (int f = 0; f < 4; ++f) bf[f] = *(const bfx8*)&lB[boff[f]];
        #pragma unroll
        for (int fm = 0; fm < 4; ++fm)
            #pragma unroll
            for (int fn = 0; fn < 4; ++fn)
                acc[fm][fn] = MFMA16(af[fm], bf[fn], acc[fm][fn], 0, 0, 0);
    }

    if (CT_OUT) {
        u16* CT = (u16*)Cb + (size_t)which * sWhich + (size_t)b * sC;
        #pragma unroll
        for (int fm = 0; fm < 4; ++fm) {
            int mg = m0 + wm + fm * 16 + kh * 4;
            float bi0 = bias[mg], bi1 = bias[mg + 1], bi2 = bias[mg + 2], bi3 = bias[mg + 3];
            #pragma unroll
            for (int fn = 0; fn < 4; ++fn) {
                int ng = n0 + wn + fn * 16 + rl;
                float v0 = acc[fm][fn][0] + bi0;
                float v1 = acc[fm][fn][1] + bi1;
                float v2 = acc[fm][fn][2] + bi2;
                float v3 = acc[fm][fn][3] + bi3;
                if (RELU) {
                    v0 = fmaxf(v0, 0.f); v1 = fmaxf(v1, 0.f);
                    v2 = fmaxf(v2, 0.f); v3 = fmaxf(v3, 0.f);
                }
                us4 o = { f2b(v0), f2b(v1), f2b(v2), f2b(v3) };
                *(us4*)(CT + (size_t)ng * M + mg) = o;
            }
        }
    } else {
        float* C = (float*)Cb + (size_t)b * sC;
        #pragma unroll
        for (int fm = 0; fm < 4; ++fm) {
            int mg = m0 + wm + fm * 16 + kh * 4;
            #pragma unroll
            for (int fn = 0; fn < 4; ++fn) {
                int ng = n0 + wn + fn * 16 + rl;
                #pragma unroll
                for (int r = 0; r < 4; ++r) {
                    float v = acc[fm][fn][r] + bias[mg + r];
                    if (RELU) v = fmaxf(v, 0.f);
                    C[(size_t)(mg + r) * N + ng] = v;
                }
            }
        }
    }
}

// ---------------------------------------------------------------------------
// Pass A: softmax stats. Block = 64 l-rows of one (b,h). grid (L/64, B*H).
// att^T tile = mfma(A=kT rows m, BT=qT rows l); per-lane online (max,sum) over m.
// ---------------------------------------------------------------------------
__global__ __launch_bounds__(256) void attn_stats(
    const u16* __restrict__ qT, const u16* __restrict__ kT,
    float* __restrict__ rmax, float* __restrict__ rinv)
{
    const int lt = blockIdx.x;
    const int bh = blockIdx.y;
    const int b = bh >> 5, h = bh & 31;
    const size_t base = (size_t)b * L * AF + h * DH;

    __shared__ u16 lq[64 * 64];
    __shared__ u16 lk[64 * 64];
    __shared__ float sM[4][64], sS[4][64];

    const int t = threadIdx.x, lane = t & 63, wave = t >> 6;
    const int rl = lane & 15, g = lane >> 4;

    // staging: 512 slots of 16B; slot -> row s>>3, chunk-pos s&7; src = pos ^ (r&7)
    const int s0 = t, s1 = t + 256;
    const int r0 = s0 >> 3, cs0 = (s0 & 7) ^ (r0 & 7);
    const int r1 = s1 >> 3, cs1 = (s1 & 7) ^ (r1 & 7);

    gld16(qT + base + (size_t)(lt * 64 + r0) * AF + cs0 * 8, lq + s0 * 8);
    gld16(qT + base + (size_t)(lt * 64 + r1) * AF + cs1 * 8, lq + s1 * 8);

    float Mx[4], Sx[4];
    #pragma unroll
    for (int f = 0; f < 4; ++f) { Mx[f] = -1e30f; Sx[f] = 0.f; }

    const int rmr = wave * 16 + rl;
    const int akoff0 = rmr * 64 + ((g ^ (rmr & 7)) * 8);
    const int akoff1 = rmr * 64 + (((g + 4) ^ (rmr & 7)) * 8);
    int qoff0[4], qoff1[4];
    #pragma unroll
    for (int f = 0; f < 4; ++f) {
        int rq = f * 16 + rl;
        qoff0[f] = rq * 64 + ((g ^ (rq & 7)) * 8);
        qoff1[f] = rq * 64 + (((g + 4) ^ (rq & 7)) * 8);
    }

    const u16* gk0 = kT + base + (size_t)r0 * AF + cs0 * 8;
    const u16* gk1 = kT + base + (size_t)r1 * AF + cs1 * 8;

    for (int mt = 0; mt < 16; ++mt) {
        __syncthreads();
        gld16(gk0 + (size_t)mt * 64 * AF, lk + s0 * 8);
        gld16(gk1 + (size_t)mt * 64 * AF, lk + s1 * 8);
        __syncthreads();
        bfx8 ak0 = *(const bfx8*)&lk[akoff0];
        bfx8 ak1 = *(const bfx8*)&lk[akoff1];
        #pragma unroll
        for (int fn = 0; fn < 4; ++fn) {
            bfx8 q0 = *(const bfx8*)&lq[qoff0[fn]];
            bfx8 q1 = *(const bfx8*)&lq[qoff1[fn]];
            fx4 att = (fx4){0.f, 0.f, 0.f, 0.f};
            att = MFMA16(ak0, q0, att, 0, 0, 0);
            att = MFMA16(ak1, q1, att, 0, 0, 0);
            const int lg = lt * 64 + fn * 16 + rl;
            const int mb = mt * 64 + wave * 16 + g * 4;
            float sv0 = (att[0] - fabsf((float)(lg - (mb + 0)))) * 0.125f;
            float sv1 = (att[1] - fabsf((float)(lg - (mb + 1)))) * 0.125f;
            float sv2 = (att[2] - fabsf((float)(lg - (mb + 2)))) * 0.125f;
            float sv3 = (att[3] - fabsf((float)(lg - (mb + 3)))) * 0.125f;
            float tm = fmaxf(fmaxf(sv0, sv1), fmaxf(sv2, sv3));
            if (tm > Mx[fn]) { Sx[fn] *= __expf(Mx[fn] - tm); Mx[fn] = tm; }
            Sx[fn] += __expf(sv0 - Mx[fn]) + __expf(sv1 - Mx[fn])
                    + __expf(sv2 - Mx[fn]) + __expf(sv3 - Mx[fn]);
        }
    }
    #pragma unroll
    for (int fn = 0; fn < 4; ++fn) {
        float m_ = Mx[fn], s_ = Sx[fn];
        #pragma unroll
        for (int off = 16; off <= 32; off <<= 1) {
            float m2 = __shfl_xor(m_, off);
            float s2 = __shfl_xor(s_, off);
            float mn = fmaxf(m_, m2);
            s_ = s_ * __expf(m_ - mn) + s2 * __expf(m2 - mn);
            m_ = mn;
        }
        if (lane < 16) { sM[wave][fn * 16 + rl] = m_; sS[wave][fn * 16 + rl] = s_; }
    }
    __syncthreads();
    if (t < 64) {
        float m_ = sM[0][t], s_ = sS[0][t];
        #pragma unroll
        for (int w = 1; w < 4; ++w) {
            float m2 = sM[w][t], s2 = sS[w][t];
            float mn = fmaxf(m_, m2);
            s_ = s_ * __expf(m_ - mn) + s2 * __expf(m2 - mn);
            m_ = mn;
        }
        rmax[(size_t)bh * L + lt * 64 + t] = m_;
        rinv[(size_t)bh * L + lt * 64 + t] = 1.0f / s_;
    }
}

// ---------------------------------------------------------------------------
// Pass B: O[d,m] = sum_{l<=m} v[d,l]*w[l,m]; h = relu(O) -> hT[b][m][h*64+d].
// Block = (b,h) x m-tile-pair (mt, 15-mt): 17 l-tile units each (balanced).
// grid (8, B*H).
// ---------------------------------------------------------------------------
__global__ __launch_bounds__(256) void attn_pv(
    const u16* __restrict__ qT, const u16* __restrict__ kT, const u16* __restrict__ v,
    const float* __restrict__ rmax, const float* __restrict__ rinv,
    u16* __restrict__ hT)
{
    const int pair = blockIdx.x;
    const int bh = blockIdx.y;
    const int b = bh >> 5, h = bh & 31;
    const size_t qkbase = (size_t)b * L * AF + h * DH;
    const size_t vbase  = ((size_t)b * AF + h * DH) * L;
    const size_t rbase  = (size_t)bh * L;

    __shared__ u16 lkt[64 * 64], lqt[64 * 64], lv[64 * 64];
    __shared__ u16 lw[64 * 68];   // wT[m][l], pad 68 (writes conflict-free)

    const int t = threadIdx.x, lane = t & 63, wave = t >> 6;
    const int rl = lane & 15, g = lane >> 4;

    const int s0 = t, s1 = t + 256;
    const int r0 = s0 >> 3, cs0 = (s0 & 7) ^ (r0 & 7);
    const int r1 = s1 >> 3, cs1 = (s1 & 7) ^ (r1 & 7);

    const u16* gq0 = qT + qkbase + (size_t)r0 * AF + cs0 * 8;
    const u16* gq1 = qT + qkbase + (size_t)r1 * AF + cs1 * 8;
    const u16* gv0 = v + vbase + (size_t)r0 * L + cs0 * 8;
    const u16* gv1 = v + vbase + (size_t)r1 * L + cs1 * 8;

    const int rmr = wave * 16 + rl;     // phase-1 A rows (m), phase-2 A rows (d)
    const int toff0 = rmr * 64 + ((g ^ (rmr & 7)) * 8);
    const int toff1 = rmr * 64 + (((g + 4) ^ (rmr & 7)) * 8);
    int qoff0[4], qoff1[4];
    #pragma unroll
    for (int f = 0; f < 4; ++f) {
        int rq = f * 16 + rl;
        qoff0[f] = rq * 64 + ((g ^ (rq & 7)) * 8);
        qoff1[f] = rq * 64 + (((g + 4) ^ (rq & 7)) * 8);
    }

    for (int half = 0; half < 2; ++half) {
        const int mt = half ? pair : 15 - pair;
        const int m0 = mt * 64;
        __syncthreads();   // previous half's phase-2 done with lv/lw; lkt free
        gld16(kT + qkbase + (size_t)(m0 + r0) * AF + cs0 * 8, lkt + s0 * 8);
        gld16(kT + qkbase + (size_t)(m0 + r1) * AF + cs1 * 8, lkt + s1 * 8);

        fx4 oa[4];
        #pragma unroll
        for (int f = 0; f < 4; ++f) oa[f] = (fx4){0.f, 0.f, 0.f, 0.f};

        for (int lt = 0; lt <= mt; ++lt) {
            __syncthreads();   // prev phase-2 done reading lv/lw; drains lkt gld (iter 0)
            gld16(gq0 + (size_t)lt * 64 * AF, lqt + s0 * 8);
            gld16(gq1 + (size_t)lt * 64 * AF, lqt + s1 * 8);
            gld16(gv0 + lt * 64, lv + s0 * 8);
            gld16(gv1 + lt * 64, lv + s1 * 8);
            __syncthreads();   // all stages complete

            // phase 1: att^T[m][l] = mfma(kT rows m, qT rows l); -> weights in lw
            bfx8 ak0 = *(const bfx8*)&lkt[toff0];
            bfx8 ak1 = *(const bfx8*)&lkt[toff1];
            #pragma unroll
            for (int fn = 0; fn < 4; ++fn) {
                bfx8 q0 = *(const bfx8*)&lqt[qoff0[fn]];
                bfx8 q1 = *(const bfx8*)&lqt[qoff1[fn]];
                fx4 att = (fx4){0.f, 0.f, 0.f, 0.f};
                att = MFMA16(ak0, q0, att, 0, 0, 0);
                att = MFMA16(ak1, q1, att, 0, 0, 0);
                const int lg = lt * 64 + fn * 16 + rl;
                float rm = rmax[rbase + lg];
                float ri = rinv[rbase + lg];
                #pragma unroll
                for (int r = 0; r < 4; ++r) {
                    int mloc = wave * 16 + g * 4 + r;
                    int mg = m0 + mloc;
                    float s = (att[r] - fabsf((float)(lg - mg))) * 0.125f;
                    float w = (lg <= mg) ? __expf(s - rm) * ri : 0.f;
                    lw[mloc * 68 + fn * 16 + rl] = f2b(w);
                }
            }
            __syncthreads();   // lw complete

            // phase 2: O[d][m] += mfma(v rows d, wT rows m)
            bfx8 av0 = *(const bfx8*)&lv[toff0];
            bfx8 av1 = *(const bfx8*)&lv[toff1];
            #pragma unroll
            for (int fn = 0; fn < 4; ++fn) {
                const u16* wrow = &lw[(fn * 16 + rl) * 68];
                union { bfx8 f; bfx4 h[2]; } w0, w1;   // 8B-aligned b64 pair loads
                w0.h[0] = *(const bfx4*)&wrow[g * 8];
                w0.h[1] = *(const bfx4*)&wrow[g * 8 + 4];
                w1.h[0] = *(const bfx4*)&wrow[(g + 4) * 8];
                w1.h[1] = *(const bfx4*)&wrow[(g + 4) * 8 + 4];
                oa[fn] = MFMA16(av0, w0.f, oa[fn], 0, 0, 0);
                oa[fn] = MFMA16(av1, w1.f, oa[fn], 0, 0, 0);
            }
        }

        // epilogue: relu, C^T store -> hT[b][m][h*64+d]
        #pragma unroll
        for (int fn = 0; fn < 4; ++fn) {
            int mg = m0 + fn * 16 + rl;
            int cg = h * DH + wave * 16 + g * 4;
            us4 o = { f2b(fmaxf(oa[fn][0], 0.f)), f2b(fmaxf(oa[fn][1], 0.f)),
                      f2b(fmaxf(oa[fn][2], 0.f)), f2b(fmaxf(oa[fn][3], 0.f)) };
            *(us4*)(hT + ((size_t)b * L + mg) * AF + cg) = o;
        }
    }
}

// ---------------------------------------------------------------------------
extern "C" void kernel_launch(void* const* d_in, const int* in_sizes, int n_in,
                              void* d_out, int out_size, void* d_ws, size_t ws_size,
                              hipStream_t stream)
{
    (void)in_sizes; (void)n_in; (void)out_size; (void)ws_size;
    const float* x  = (const float*)d_in[0];
    const float* Wq = (const float*)d_in[1];
    const float* bq = (const float*)d_in[2];
    const float* Wk = (const float*)d_in[3];
    const float* bk = (const float*)d_in[4];
    const float* Wv = (const float*)d_in[5];
    const float* bv = (const float*)d_in[6];
    const float* W1 = (const float*)d_in[7];
    const float* b1 = (const float*)d_in[8];
    const float* W2 = (const float*)d_in[9];
    const float* b2 = (const float*)d_in[10];

    u16* wsp = (u16*)d_ws;
    size_t o = 0;
    u16* xT  = wsp + o; o += (size_t)NB * L * CIN;     // 1,048,576
    u16* qT  = wsp + o; o += (size_t)NB * L * AF;      // 4,194,304
    u16* kT  = wsp + o; o += (size_t)NB * L * AF;
    u16* vT  = wsp + o; o += (size_t)NB * L * AF;
    u16* vdm = wsp + o; o += (size_t)NB * AF * L;
    u16* hT  = wsp + o; o += (size_t)NB * L * AF;
    u16* z1T = wsp + o; o += (size_t)NB * L * AF;
    u16* Wqb = wsp + o; o += (size_t)AF * CIN;
    u16* Wkb = wsp + o; o += (size_t)AF * CIN;
    u16* Wvb = wsp + o; o += (size_t)AF * CIN;
    u16* W1b = wsp + o; o += (size_t)AF * AF;
    u16* W2b = wsp + o; o += (size_t)AF * AF;
    float* rmax = (float*)(wsp + o); o += (size_t)NB * NH * L * 2;
    float* rinv = (float*)(wsp + o); o += (size_t)NB * NH * L * 2;

    dim3 blk(256);

    convert_xT<<<dim3(CIN / 64, L / 64, NB), blk, 0, stream>>>(x, xT);
    convert_f2b4<<<dim3(1024), blk, 0, stream>>>(Wq, Wqb, AF * CIN / 4);
    convert_f2b4<<<dim3(1024), blk, 0, stream>>>(Wk, Wkb, AF * CIN / 4);
    convert_f2b4<<<dim3(1024), blk, 0, stream>>>(Wv, Wvb, AF * CIN / 4);
    convert_f2b4<<<dim3(2048), blk, 0, stream>>>(W1, W1b, AF * AF / 4);
    convert_f2b4<<<dim3(2048), blk, 0, stream>>>(W2, W2b, AF * AF / 4);

    // QKV: qT/kT/vT = (W? * x)^T, fused over {q,k,v} x {b}: grid.z = b*3+which
    gemm_bt<0, 1, 3><<<dim3(L / 128, AF / 128, NB * 3), blk, 0, stream>>>(
        Wqb, Wkb, Wvb, bq, bk, bv, xT, qT,
        AF, L, CIN, (size_t)L * CIN, (size_t)L * AF, (size_t)NB * L * AF);

    transpose_b<<<dim3(AF / 64, L / 64, NB), blk, 0, stream>>>(vT, vdm);
    attn_stats<<<dim3(L / 64, NB * NH), blk, 0, stream>>>(qT, kT, rmax, rinv);
    attn_pv<<<dim3(8, NB * NH), blk, 0, stream>>>(qT, kT, vdm, rmax, rinv, hT);

    // z1T = relu(W1*h + b1)^T
    gemm_bt<1, 1, 1><<<dim3(L / 128, AF / 128, NB), blk, 0, stream>>>(
        W1b, nullptr, nullptr, b1, nullptr, nullptr, hT, z1T,
        AF, L, AF, (size_t)L * AF, (size_t)L * AF, 0);
    // out = W2*z1 + b2 (fp32, normal orientation)
    gemm_bt<0, 0, 1><<<dim3(L / 128, AF / 128, NB), blk, 0, stream>>>(
        W2b, nullptr, nullptr, b2, nullptr, nullptr, z1T, d_out,
        AF, L, AF, (size_t)L * AF, (size_t)AF * L, 0);
}

// Round 4
// 182.765 us; speedup vs baseline: 1.2270x; 1.2270x over previous
//
#include <hip/hip_runtime.h>

#define L 1024
#define CIN 512
#define NH 32
#define DH 64
#define NB 2
#define AF 2048

typedef unsigned short u16;
typedef unsigned int u32;
typedef __attribute__((ext_vector_type(8))) short bfx8;   // 8 bf16 = 4 VGPR (MFMA A/B frag)
typedef __attribute__((ext_vector_type(4))) short bfx4;   // 8B half-frag
typedef __attribute__((ext_vector_type(4))) float fx4;    // MFMA C/D frag

struct __align__(8) us4 { u16 x, y, z, w; };

#define MFMA16 __builtin_amdgcn_mfma_f32_16x16x32_bf16
#define SBAR() __builtin_amdgcn_s_barrier()
#define SFENCE() __builtin_amdgcn_sched_barrier(0)
#define WAIT_VM(N) asm volatile("s_waitcnt vmcnt(" #N ")" ::: "memory")
#define WAIT_LGKM0() asm volatile("s_waitcnt lgkmcnt(0)" ::: "memory")

__device__ inline void gld16(const void* g, void* l) {
    __builtin_amdgcn_global_load_lds(
        (const __attribute__((address_space(1))) u32*)g,
        (__attribute__((address_space(3))) u32*)l, 16, 0, 0);
}

__device__ inline u16 f2b(float f) {
    union { float f; u32 u; } v; v.f = f;
    u32 u = v.u;
    return (u16)((u + 0x7fffu + ((u >> 16) & 1u)) >> 16);
}

// ---------------------------------------------------------------------------
// Fused weight converts: fp32 -> bf16, up to 3 tensors via grid.z.
// ---------------------------------------------------------------------------
__global__ __launch_bounds__(256) void convert_f2b_multi(
    const float* __restrict__ in0, const float* __restrict__ in1, const float* __restrict__ in2,
    u16* __restrict__ out0, u16* __restrict__ out1, u16* __restrict__ out2, int n4)
{
    const float* in = blockIdx.z == 0 ? in0 : blockIdx.z == 1 ? in1 : in2;
    u16* out = blockIdx.z == 0 ? out0 : blockIdx.z == 1 ? out1 : out2;
    int i = blockIdx.x * 256 + threadIdx.x;
    int stride = gridDim.x * 256;
    for (; i < n4; i += stride) {
        float4 v = ((const float4*)in)[i];
        us4 o = { f2b(v.x), f2b(v.y), f2b(v.z), f2b(v.w) };
        ((us4*)out)[i] = o;
    }
}

// ---------------------------------------------------------------------------
// x [B][CIN][L] fp32 -> xT [B][L][CIN] bf16 (transpose + convert)
// grid (CIN/64, L/64, B), block 256
// ---------------------------------------------------------------------------
__global__ __launch_bounds__(256) void convert_xT(
    const float* __restrict__ x, u16* __restrict__ xT)
{
    const int c0 = blockIdx.x * 64, l0 = blockIdx.y * 64, b = blockIdx.z;
    __shared__ u16 tile[64][68];   // [c][l]
    const int t = threadIdx.x;
    const int tr = t >> 4, tc4 = (t & 15) * 4;
    #pragma unroll
    for (int p = 0; p < 4; ++p) {
        int c = p * 16 + tr;
        float4 v = *(const float4*)(x + ((size_t)(b * CIN + c0 + c)) * L + l0 + tc4);
        tile[c][tc4 + 0] = f2b(v.x); tile[c][tc4 + 1] = f2b(v.y);
        tile[c][tc4 + 2] = f2b(v.z); tile[c][tc4 + 3] = f2b(v.w);
    }
    __syncthreads();
    #pragma unroll
    for (int p = 0; p < 4; ++p) {
        int l = p * 16 + tr;
        us4 o = { tile[tc4 + 0][l], tile[tc4 + 1][l], tile[tc4 + 2][l], tile[tc4 + 3][l] };
        *(us4*)(xT + ((size_t)(b * L + l0 + l)) * CIN + c0 + tc4) = o;
    }
}

// ---------------------------------------------------------------------------
// MFMA GEMM, depth-2 counted-vmcnt pipeline (4 LDS buffers, 1 barrier/K-step).
// C[M,N] = A[M,K] * B[K,N] (+bias[M], opt relu). A row-major, BT=[N][K].
// CT_OUT=1: store C^T bf16 [N][M].  CT_OUT=0: store C fp32 [M][N].
// NA=3 (QKV): grid.z = b*3+which; which==0 scales output by 0.125 (q/sqrt(D));
//             which==2 stores NORMAL orientation bf16 [b][M][N] into Cb2.
// 128x128 tile, BK=32, 256 threads (4 waves of 64x64).
// ---------------------------------------------------------------------------
template<int RELU, int CT_OUT, int NA>
__global__ __launch_bounds__(256) void gemm_bt(
    const u16* __restrict__ A0, const u16* __restrict__ A1, const u16* __restrict__ A2,
    const float* __restrict__ bias0, const float* __restrict__ bias1, const float* __restrict__ bias2,
    const u16* __restrict__ BTb, void* __restrict__ Cb, void* __restrict__ Cb2,
    int M, int N, int K, size_t sBT, size_t sC, size_t sWhich)
{
    const int z = blockIdx.z;
    const int which = (NA == 3) ? (z % 3) : 0;
    const int b     = (NA == 3) ? (z / 3) : z;
    const u16* __restrict__ A = (which == 0) ? A0 : (which == 1) ? A1 : A2;
    const float* __restrict__ bias = (which == 0) ? bias0 : (which == 1) ? bias1 : bias2;
    const u16* __restrict__ BT = BTb + (size_t)b * sBT;
    const int m0 = blockIdx.y * 128, n0 = blockIdx.x * 128;

    __shared__ u16 lA[4][128 * 32];
    __shared__ u16 lB[4][128 * 32];

    const int t = threadIdx.x, lane = t & 63, wave = t >> 6;
    const int wm = (wave >> 1) * 64, wn = (wave & 1) * 64;
    const int rl = lane & 15, kh = lane >> 4;

    fx4 acc[4][4];
    #pragma unroll
    for (int i = 0; i < 4; ++i)
        #pragma unroll
        for (int j = 0; j < 4; ++j) acc[i][j] = (fx4){0.f, 0.f, 0.f, 0.f};

    // staging: 512 16B-slots; slot s -> row s>>2, chunk-pos s&3; src chunk = pos ^ ((r>>1)&3)
    const int s0 = t, s1 = t + 256;
    const int r0 = s0 >> 2, cs0 = (s0 & 3) ^ ((r0 >> 1) & 3);
    const int r1 = s1 >> 2, cs1 = (s1 & 3) ^ ((r1 >> 1) & 3);
    const u16* gA0 = A  + (size_t)(m0 + r0) * K + cs0 * 8;
    const u16* gA1 = A  + (size_t)(m0 + r1) * K + cs1 * 8;
    const u16* gB0 = BT + (size_t)(n0 + r0) * K + cs0 * 8;
    const u16* gB1 = BT + (size_t)(n0 + r1) * K + cs1 * 8;

    // frag read offsets: row r, k-chunk kh -> r*32 + ((kh ^ ((r>>1)&3))*8)
    int aoff[4], boff[4];
    #pragma unroll
    for (int f = 0; f < 4; ++f) {
        int ra = wm + f * 16 + rl;
        int rb = wn + f * 16 + rl;
        aoff[f] = ra * 32 + ((kh ^ ((ra >> 1) & 3)) * 8);
        boff[f] = rb * 32 + ((kh ^ ((rb >> 1) & 3)) * 8);
    }

    const int NT = K >> 5;   // >= 16 always here
    // prologue: stage tiles 0,1
    gld16(gA0 + 0, &lA[0][s0 * 8]);  gld16(gA1 + 0, &lA[0][s1 * 8]);
    gld16(gB0 + 0, &lB[0][s0 * 8]);  gld16(gB1 + 0, &lB[0][s1 * 8]);
    gld16(gA0 + 32, &lA[1][s0 * 8]); gld16(gA1 + 32, &lA[1][s1 * 8]);
    gld16(gB0 + 32, &lB[1][s0 * 8]); gld16(gB1 + 32, &lB[1][s1 * 8]);
    WAIT_VM(4); SBAR(); SFENCE();

    for (int it = 0; it < NT; ++it) {
        if (it + 2 < NT) {
            const int bf = (it + 2) & 3, k0 = (it + 2) << 5;
            gld16(gA0 + k0, &lA[bf][s0 * 8]);
            gld16(gA1 + k0, &lA[bf][s1 * 8]);
            gld16(gB0 + k0, &lB[bf][s0 * 8]);
            gld16(gB1 + k0, &lB[bf][s1 * 8]);
            WAIT_VM(8);          // tile `it` (oldest 4) complete; 8 newest in flight
        } else if (it + 1 < NT) {
            WAIT_VM(4);
        } else {
            WAIT_VM(0);
        }
        SBAR(); SFENCE();
        const u16* bA = lA[it & 3];
        const u16* bB = lB[it & 3];
        bfx8 af[4], bfr[4];
        #pragma unroll
        for (int f = 0; f < 4; ++f) af[f] = *(const bfx8*)&bA[aoff[f]];
        #pragma unroll
        for (int f = 0; f < 4; ++f) bfr[f] = *(const bfx8*)&bB[boff[f]];
        __builtin_amdgcn_s_setprio(1);
        #pragma unroll
        for (int fm = 0; fm < 4; ++fm)
            #pragma unroll
            for (int fn = 0; fn < 4; ++fn)
                acc[fm][fn] = MFMA16(af[fm], bfr[fn], acc[fm][fn], 0, 0, 0);
        __builtin_amdgcn_s_setprio(0);
    }

    if (NA == 3 && which == 2) {
        // v: store normal orientation bf16 [b][M][N]
        u16* Vn = (u16*)Cb2 + (size_t)b * (size_t)M * N;
        #pragma unroll
        for (int fm = 0; fm < 4; ++fm) {
            int mg = m0 + wm + fm * 16 + kh * 4;
            #pragma unroll
            for (int fn = 0; fn < 4; ++fn) {
                int ng = n0 + wn + fn * 16 + rl;
                #pragma unroll
                for (int r = 0; r < 4; ++r)
                    Vn[(size_t)(mg + r) * N + ng] = f2b(acc[fm][fn][r] + bias[mg + r]);
            }
        }
    } else if (CT_OUT) {
        const float sc = (NA == 3 && which == 0) ? 0.125f : 1.0f;
        u16* CT = (u16*)Cb + (size_t)which * sWhich + (size_t)b * sC;
        #pragma unroll
        for (int fm = 0; fm < 4; ++fm) {
            int mg = m0 + wm + fm * 16 + kh * 4;
            float bi0 = bias[mg], bi1 = bias[mg + 1], bi2 = bias[mg + 2], bi3 = bias[mg + 3];
            #pragma unroll
            for (int fn = 0; fn < 4; ++fn) {
                int ng = n0 + wn + fn * 16 + rl;
                float v0 = (acc[fm][fn][0] + bi0) * sc;
                float v1 = (acc[fm][fn][1] + bi1) * sc;
                float v2 = (acc[fm][fn][2] + bi2) * sc;
                float v3 = (acc[fm][fn][3] + bi3) * sc;
                if (RELU) {
                    v0 = fmaxf(v0, 0.f); v1 = fmaxf(v1, 0.f);
                    v2 = fmaxf(v2, 0.f); v3 = fmaxf(v3, 0.f);
                }
                us4 o = { f2b(v0), f2b(v1), f2b(v2), f2b(v3) };
                *(us4*)(CT + (size_t)ng * M + mg) = o;
            }
        }
    } else {
        float* C = (float*)Cb + (size_t)b * sC;
        #pragma unroll
        for (int fm = 0; fm < 4; ++fm) {
            int mg = m0 + wm + fm * 16 + kh * 4;
            #pragma unroll
            for (int fn = 0; fn < 4; ++fn) {
                int ng = n0 + wn + fn * 16 + rl;
                #pragma unroll
                for (int r = 0; r < 4; ++r) {
                    float v = acc[fm][fn][r] + bias[mg + r];
                    if (RELU) v = fmaxf(v, 0.f);
                    C[(size_t)(mg + r) * N + ng] = v;
                }
            }
        }
    }
}

// ---------------------------------------------------------------------------
// Pass A: S[l] = sum_m exp(att[l,m] - |l-m|/8)  (q pre-scaled by 1/8; no max:
// |s| <= ~10 so fp32 exp is safe).  Block = 64 l-rows of one (b,h).
// grid (L/64, B*H).  Depth-2 prefetch on k-tiles.
// ---------------------------------------------------------------------------
__global__ __launch_bounds__(256) void attn_stats(
    const u16* __restrict__ qT, const u16* __restrict__ kT,
    float* __restrict__ rinv)
{
    const int lt = blockIdx.x;
    const int bh = blockIdx.y;
    const int b = bh >> 5, h = bh & 31;
    const size_t base = (size_t)b * L * AF + h * DH;

    __shared__ u16 lq[64 * 64];
    __shared__ u16 lk[4][64 * 64];
    __shared__ float sS[4][64];

    const int t = threadIdx.x, lane = t & 63, wave = t >> 6;
    const int rl = lane & 15, g = lane >> 4;

    // staging: 512 slots of 16B; slot -> row s>>3, chunk-pos s&7; src = pos ^ (r&7)
    const int s0 = t, s1 = t + 256;
    const int r0 = s0 >> 3, cs0 = (s0 & 7) ^ (r0 & 7);
    const int r1 = s1 >> 3, cs1 = (s1 & 7) ^ (r1 & 7);

    const u16* gk0 = kT + base + (size_t)r0 * AF + cs0 * 8;
    const u16* gk1 = kT + base + (size_t)r1 * AF + cs1 * 8;

    gld16(qT + base + (size_t)(lt * 64 + r0) * AF + cs0 * 8, lq + s0 * 8);
    gld16(qT + base + (size_t)(lt * 64 + r1) * AF + cs1 * 8, lq + s1 * 8);
    gld16(gk0, &lk[0][s0 * 8]);
    gld16(gk1, &lk[0][s1 * 8]);
    gld16(gk0 + (size_t)64 * AF, &lk[1][s0 * 8]);
    gld16(gk1 + (size_t)64 * AF, &lk[1][s1 * 8]);
    WAIT_VM(2); SBAR(); SFENCE();    // q + k0 landed

    const int rmr = wave * 16 + rl;
    const int akoff0 = rmr * 64 + ((g ^ (rmr & 7)) * 8);
    const int akoff1 = rmr * 64 + (((g + 4) ^ (rmr & 7)) * 8);
    bfx8 qf0[4], qf1[4];
    #pragma unroll
    for (int f = 0; f < 4; ++f) {
        int rq = f * 16 + rl;
        qf0[f] = *(const bfx8*)&lq[rq * 64 + ((g ^ (rq & 7)) * 8)];
        qf1[f] = *(const bfx8*)&lq[rq * 64 + (((g + 4) ^ (rq & 7)) * 8)];
    }

    float Sx[4] = {0.f, 0.f, 0.f, 0.f};
    for (int mt = 0; mt < 16; ++mt) {
        if (mt + 2 < 16) {
            const int bf = (mt + 2) & 3;
            gld16(gk0 + (size_t)(mt + 2) * 64 * AF, &lk[bf][s0 * 8]);
            gld16(gk1 + (size_t)(mt + 2) * 64 * AF, &lk[bf][s1 * 8]);
            WAIT_VM(4);
        } else if (mt + 1 < 16) {
            WAIT_VM(2);
        } else {
            WAIT_VM(0);
        }
        SBAR(); SFENCE();
        const u16* kb = lk[mt & 3];
        bfx8 ak0 = *(const bfx8*)&kb[akoff0];
        bfx8 ak1 = *(const bfx8*)&kb[akoff1];
        const float mb = (float)(mt * 64 + wave * 16 + g * 4);
        #pragma unroll
        for (int fn = 0; fn < 4; ++fn) {
            fx4 att = (fx4){0.f, 0.f, 0.f, 0.f};
            att = MFMA16(ak0, qf0[fn], att, 0, 0, 0);
            att = MFMA16(ak1, qf1[fn], att, 0, 0, 0);
            const float lgf = (float)(lt * 64 + fn * 16 + rl);
            float e0 = __expf(att[0] - 0.125f * fabsf(lgf - mb));
            float e1 = __expf(att[1] - 0.125f * fabsf(lgf - (mb + 1.f)));
            float e2 = __expf(att[2] - 0.125f * fabsf(lgf - (mb + 2.f)));
            float e3 = __expf(att[3] - 0.125f * fabsf(lgf - (mb + 3.f)));
            Sx[fn] += (e0 + e1) + (e2 + e3);
        }
    }
    #pragma unroll
    for (int fn = 0; fn < 4; ++fn) {
        float s_ = Sx[fn];
        s_ += __shfl_xor(s_, 16);
        s_ += __shfl_xor(s_, 32);
        if (lane < 16) sS[wave][fn * 16 + rl] = s_;
    }
    __syncthreads();
    if (t < 64) {
        float s_ = sS[0][t] + sS[1][t] + sS[2][t] + sS[3][t];
        rinv[(size_t)bh * L + lt * 64 + t] = 1.0f / s_;
    }
}

// ---------------------------------------------------------------------------
// Pass B: O[d,m] = sum_{l<=m} v[d,l] * exp(s[l,m]) * rinv[l]; h=relu(O) -> hT.
// Block = (b,h) x m-tile-pair (mt, 15-mt): 17 l-units each. grid (8, B*H).
// Double-buffered q/v prefetch; raw barriers (no vmcnt drain mid-iter).
// ---------------------------------------------------------------------------
__global__ __launch_bounds__(256) void attn_pv(
    const u16* __restrict__ qT, const u16* __restrict__ kT, const u16* __restrict__ v,
    const float* __restrict__ rinv, u16* __restrict__ hT)
{
    const int pair = blockIdx.x;
    const int bh = blockIdx.y;
    const int b = bh >> 5, h = bh & 31;
    const size_t qkbase = (size_t)b * L * AF + h * DH;
    const size_t vbase  = ((size_t)b * AF + h * DH) * L;
    const size_t rbase  = (size_t)bh * L;

    __shared__ u16 lkt[64 * 64];
    __shared__ u16 lqt[2][64 * 64], lv[2][64 * 64];
    __shared__ u16 lw[64 * 68];   // wT[m][l], pad 68

    const int t = threadIdx.x, lane = t & 63, wave = t >> 6;
    const int rl = lane & 15, g = lane >> 4;

    const int s0 = t, s1 = t + 256;
    const int r0 = s0 >> 3, cs0 = (s0 & 7) ^ (r0 & 7);
    const int r1 = s1 >> 3, cs1 = (s1 & 7) ^ (r1 & 7);

    const u16* gq0 = qT + qkbase + (size_t)r0 * AF + cs0 * 8;
    const u16* gq1 = qT + qkbase + (size_t)r1 * AF + cs1 * 8;
    const u16* gv0 = v + vbase + (size_t)r0 * L + cs0 * 8;
    const u16* gv1 = v + vbase + (size_t)r1 * L + cs1 * 8;

    const int rmr = wave * 16 + rl;     // phase-1 A rows (m), phase-2 A rows (d)
    const int toff0 = rmr * 64 + ((g ^ (rmr & 7)) * 8);
    const int toff1 = rmr * 64 + (((g + 4) ^ (rmr & 7)) * 8);
    int qoff0[4], qoff1[4];
    #pragma unroll
    for (int f = 0; f < 4; ++f) {
        int rq = f * 16 + rl;
        qoff0[f] = rq * 64 + ((g ^ (rq & 7)) * 8);
        qoff1[f] = rq * 64 + (((g + 4) ^ (rq & 7)) * 8);
    }

    for (int half = 0; half < 2; ++half) {
        const int mt = half ? pair : 15 - pair;
        const int m0 = mt * 64;

        // prologue: K-tile + first q/v tile (all prior vmem drained)
        gld16(kT + qkbase + (size_t)(m0 + r0) * AF + cs0 * 8, lkt + s0 * 8);
        gld16(kT + qkbase + (size_t)(m0 + r1) * AF + cs1 * 8, lkt + s1 * 8);
        gld16(gq0, &lqt[0][s0 * 8]);
        gld16(gq1, &lqt[0][s1 * 8]);
        gld16(gv0, &lv[0][s0 * 8]);
        gld16(gv1, &lv[0][s1 * 8]);
        WAIT_VM(0); SBAR(); SFENCE();

        fx4 oa[4];
        #pragma unroll
        for (int f = 0; f < 4; ++f) oa[f] = (fx4){0.f, 0.f, 0.f, 0.f};

        int cur = 0;
        for (int lt = 0; lt <= mt; ++lt) {
            if (lt < mt) {   // prefetch next q/v tile into the other buffer
                gld16(gq0 + (size_t)(lt + 1) * 64 * AF, &lqt[cur ^ 1][s0 * 8]);
                gld16(gq1 + (size_t)(lt + 1) * 64 * AF, &lqt[cur ^ 1][s1 * 8]);
                gld16(gv0 + (lt + 1) * 64, &lv[cur ^ 1][s0 * 8]);
                gld16(gv1 + (lt + 1) * 64, &lv[cur ^ 1][s1 * 8]);
            }
            // phase 1: att^T[m][l] = mfma(kT rows m, qT rows l) -> weights in lw
            bfx8 ak0 = *(const bfx8*)&lkt[toff0];
            bfx8 ak1 = *(const bfx8*)&lkt[toff1];
            const u16* qb = lqt[cur];
            #pragma unroll
            for (int fn = 0; fn < 4; ++fn) {
                bfx8 q0 = *(const bfx8*)&qb[qoff0[fn]];
                bfx8 q1 = *(const bfx8*)&qb[qoff1[fn]];
                fx4 att = (fx4){0.f, 0.f, 0.f, 0.f};
                att = MFMA16(ak0, q0, att, 0, 0, 0);
                att = MFMA16(ak1, q1, att, 0, 0, 0);
                const int lg = lt * 64 + fn * 16 + rl;
                float ri = rinv[rbase + lg];
                const float db = (float)(lg - (m0 + wave * 16 + g * 4));
                #pragma unroll
                for (int r = 0; r < 4; ++r) {
                    int mloc = wave * 16 + g * 4 + r;
                    float s = att[r] - 0.125f * fabsf(db - (float)r);
                    float w = (lg <= m0 + mloc) ? __expf(s) * ri : 0.f;
                    lw[mloc * 68 + fn * 16 + rl] = f2b(w);
                }
            }
            WAIT_LGKM0(); SBAR(); SFENCE();   // lw visible; prefetch stays in flight

            // phase 2: O[d][m] += mfma(v rows d, wT rows m)
            const u16* vb = lv[cur];
            bfx8 av0 = *(const bfx8*)&vb[toff0];
            bfx8 av1 = *(const bfx8*)&vb[toff1];
            #pragma unroll
            for (int fn = 0; fn < 4; ++fn) {
                const u16* wrow = &lw[(fn * 16 + rl) * 68];
                union { bfx8 f; bfx4 hh[2]; } w0, w1;
                w0.hh[0] = *(const bfx4*)&wrow[g * 8];
                w0.hh[1] = *(const bfx4*)&wrow[g * 8 + 4];
                w1.hh[0] = *(const bfx4*)&wrow[(g + 4) * 8];
                w1.hh[1] = *(const bfx4*)&wrow[(g + 4) * 8 + 4];
                oa[fn] = MFMA16(av0, w0.f, oa[fn], 0, 0, 0);
                oa[fn] = MFMA16(av1, w1.f, oa[fn], 0, 0, 0);
            }
            WAIT_VM(0); WAIT_LGKM0(); SBAR(); SFENCE();   // next tile landed; reads done
            cur ^= 1;
        }

        // epilogue: relu, C^T store -> hT[b][m][h*64+d]
        #pragma unroll
        for (int fn = 0; fn < 4; ++fn) {
            int mg = m0 + fn * 16 + rl;
            int cg = h * DH + wave * 16 + g * 4;
            us4 o = { f2b(fmaxf(oa[fn][0], 0.f)), f2b(fmaxf(oa[fn][1], 0.f)),
                      f2b(fmaxf(oa[fn][2], 0.f)), f2b(fmaxf(oa[fn][3], 0.f)) };
            *(us4*)(hT + ((size_t)b * L + mg) * AF + cg) = o;
        }
    }
}

// ---------------------------------------------------------------------------
extern "C" void kernel_launch(void* const* d_in, const int* in_sizes, int n_in,
                              void* d_out, int out_size, void* d_ws, size_t ws_size,
                              hipStream_t stream)
{
    (void)in_sizes; (void)n_in; (void)out_size; (void)ws_size;
    const float* x  = (const float*)d_in[0];
    const float* Wq = (const float*)d_in[1];
    const float* bq = (const float*)d_in[2];
    const float* Wk = (const float*)d_in[3];
    const float* bk = (const float*)d_in[4];
    const float* Wv = (const float*)d_in[5];
    const float* bv = (const float*)d_in[6];
    const float* W1 = (const float*)d_in[7];
    const float* b1 = (const float*)d_in[8];
    const float* W2 = (const float*)d_in[9];
    const float* b2 = (const float*)d_in[10];

    u16* wsp = (u16*)d_ws;
    size_t o = 0;
    u16* xT  = wsp + o; o += (size_t)NB * L * CIN;
    u16* qT  = wsp + o; o += (size_t)NB * L * AF;   // q (pre-scaled by 1/8), [b][l][af]
    u16* kT  = wsp + o; o += (size_t)NB * L * AF;   // must follow qT (which*sWhich)
    u16* vdm = wsp + o; o += (size_t)NB * AF * L;   // v normal orientation [b][af][l]
    u16* hT  = wsp + o; o += (size_t)NB * L * AF;
    u16* z1T = wsp + o; o += (size_t)NB * L * AF;
    u16* Wqb = wsp + o; o += (size_t)AF * CIN;
    u16* Wkb = wsp + o; o += (size_t)AF * CIN;
    u16* Wvb = wsp + o; o += (size_t)AF * CIN;
    u16* W1b = wsp + o; o += (size_t)AF * AF;
    u16* W2b = wsp + o; o += (size_t)AF * AF;
    float* rinv = (float*)(wsp + o); o += (size_t)NB * NH * L * 2;

    dim3 blk(256);

    convert_xT<<<dim3(CIN / 64, L / 64, NB), blk, 0, stream>>>(x, xT);
    convert_f2b_multi<<<dim3(256, 1, 3), blk, 0, stream>>>(Wq, Wk, Wv, Wqb, Wkb, Wvb, AF * CIN / 4);
    convert_f2b_multi<<<dim3(1024, 1, 2), blk, 0, stream>>>(W1, W2, W2, W1b, W2b, W2b, AF * AF / 4);

    // QKV: qT/kT = (W? * x)^T (q scaled 1/8); v -> vdm normal orientation
    gemm_bt<0, 1, 3><<<dim3(L / 128, AF / 128, NB * 3), blk, 0, stream>>>(
        Wqb, Wkb, Wvb, bq, bk, bv, xT, qT, vdm,
        AF, L, CIN, (size_t)L * CIN, (size_t)L * AF, (size_t)NB * L * AF);

    attn_stats<<<dim3(L / 64, NB * NH), blk, 0, stream>>>(qT, kT, rinv);
    attn_pv<<<dim3(8, NB * NH), blk, 0, stream>>>(qT, kT, vdm, rinv, hT);

    // z1T = relu(W1*h + b1)^T
    gemm_bt<1, 1, 1><<<dim3(L / 128, AF / 128, NB), blk, 0, stream>>>(
        W1b, nullptr, nullptr, b1, nullptr, nullptr, hT, z1T, nullptr,
        AF, L, AF, (size_t)L * AF, (size_t)L * AF, 0);
    // out = W2*z1 + b2 (fp32, normal orientation)
    gemm_bt<0, 0, 1><<<dim3(L / 128, AF / 128, NB), blk, 0, stream>>>(
        W2b, nullptr, nullptr, b2, nullptr, nullptr, z1T, d_out, nullptr,
        AF, L, AF, (size_t)L * AF, (size_t)AF * L, 0);
}

// Round 5
// 181.640 us; speedup vs baseline: 1.2346x; 1.0062x over previous
//
#include <hip/hip_runtime.h>

#define L 1024
#define CIN 512
#define NH 32
#define DH 64
#define NB 2
#define AF 2048

typedef unsigned short u16;
typedef unsigned int u32;
typedef __attribute__((ext_vector_type(8))) short bfx8;   // 8 bf16 = 4 VGPR (MFMA A/B frag)
typedef __attribute__((ext_vector_type(4))) short bfx4;   // 8B half-frag
typedef __attribute__((ext_vector_type(4))) float fx4;    // MFMA C/D frag

struct __align__(8) us4 { u16 x, y, z, w; };

#define MFMA16 __builtin_amdgcn_mfma_f32_16x16x32_bf16
#define SBAR() __builtin_amdgcn_s_barrier()
#define SFENCE() __builtin_amdgcn_sched_barrier(0)
#define WAIT_VM(N) asm volatile("s_waitcnt vmcnt(" #N ")" ::: "memory")
#define WAIT_LGKM0() asm volatile("s_waitcnt lgkmcnt(0)" ::: "memory")

__device__ inline void gld16(const void* g, void* l) {
    __builtin_amdgcn_global_load_lds(
        (const __attribute__((address_space(1))) u32*)g,
        (__attribute__((address_space(3))) u32*)l, 16, 0, 0);
}

__device__ inline u16 f2b(float f) {
    union { float f; u32 u; } v; v.f = f;
    u32 u = v.u;
    return (u16)((u + 0x7fffu + ((u >> 16) & 1u)) >> 16);
}

// ---------------------------------------------------------------------------
// Fused weight converts: fp32 -> bf16, up to 3 tensors via grid.z.
// ---------------------------------------------------------------------------
__global__ __launch_bounds__(256) void convert_f2b_multi(
    const float* __restrict__ in0, const float* __restrict__ in1, const float* __restrict__ in2,
    u16* __restrict__ out0, u16* __restrict__ out1, u16* __restrict__ out2, int n4)
{
    const float* in = blockIdx.z == 0 ? in0 : blockIdx.z == 1 ? in1 : in2;
    u16* out = blockIdx.z == 0 ? out0 : blockIdx.z == 1 ? out1 : out2;
    int i = blockIdx.x * 256 + threadIdx.x;
    int stride = gridDim.x * 256;
    for (; i < n4; i += stride) {
        float4 v = ((const float4*)in)[i];
        us4 o = { f2b(v.x), f2b(v.y), f2b(v.z), f2b(v.w) };
        ((us4*)out)[i] = o;
    }
}

// ---------------------------------------------------------------------------
// x [B][CIN][L] fp32 -> xT [B][L][CIN] bf16 (transpose + convert)
// grid (CIN/64, L/64, B), block 256
// ---------------------------------------------------------------------------
__global__ __launch_bounds__(256) void convert_xT(
    const float* __restrict__ x, u16* __restrict__ xT)
{
    const int c0 = blockIdx.x * 64, l0 = blockIdx.y * 64, b = blockIdx.z;
    __shared__ u16 tile[64][68];   // [c][l]
    const int t = threadIdx.x;
    const int tr = t >> 4, tc4 = (t & 15) * 4;
    #pragma unroll
    for (int p = 0; p < 4; ++p) {
        int c = p * 16 + tr;
        float4 v = *(const float4*)(x + ((size_t)(b * CIN + c0 + c)) * L + l0 + tc4);
        tile[c][tc4 + 0] = f2b(v.x); tile[c][tc4 + 1] = f2b(v.y);
        tile[c][tc4 + 2] = f2b(v.z); tile[c][tc4 + 3] = f2b(v.w);
    }
    __syncthreads();
    #pragma unroll
    for (int p = 0; p < 4; ++p) {
        int l = p * 16 + tr;
        us4 o = { tile[tc4 + 0][l], tile[tc4 + 1][l], tile[tc4 + 2][l], tile[tc4 + 3][l] };
        *(us4*)(xT + ((size_t)(b * L + l0 + l)) * CIN + c0 + tc4) = o;
    }
}

// ---------------------------------------------------------------------------
// MFMA GEMM, depth-3 counted-vmcnt pipeline (6 LDS buffers, 1 barrier/K-step).
// C[M,N] = A[M,K] * B[K,N] (+bias[M], opt relu). A row-major, BT=[N][K].
// Tile 128(M) x 64(N), BK=32, 256 threads = 4 waves (2x2, wave-tile 64x32).
// Grid is ALWAYS (16,16,z): requires M=2048, N=1024. XCD-contiguous remap.
// CT_OUT=1: store C^T bf16 [N][M].  CT_OUT=0: store C fp32 [M][N].
// NA=3 (QKV): grid.z = b*3+which; which==0 scales output by 0.125 (q/sqrt(D));
//             which==2 stores NORMAL orientation bf16 [b][M][N] into Cb2.
// ---------------------------------------------------------------------------
template<int RELU, int CT_OUT, int NA>
__global__ __launch_bounds__(256) void gemm_bt(
    const u16* __restrict__ A0, const u16* __restrict__ A1, const u16* __restrict__ A2,
    const float* __restrict__ bias0, const float* __restrict__ bias1, const float* __restrict__ bias2,
    const u16* __restrict__ BTb, void* __restrict__ Cb, void* __restrict__ Cb2,
    int M, int N, int K, size_t sBT, size_t sC, size_t sWhich)
{
    const int z = blockIdx.z;
    const int which = (NA == 3) ? (z % 3) : 0;
    const int b     = (NA == 3) ? (z / 3) : z;
    const u16* __restrict__ A = (which == 0) ? A0 : (which == 1) ? A1 : A2;
    const float* __restrict__ bias = (which == 0) ? bias0 : (which == 1) ? bias1 : bias2;
    const u16* __restrict__ BT = BTb + (size_t)b * sBT;

    // XCD-contiguous tile remap: XCD k (= lin%8) owns 2 N-columns x all 16 M-tiles
    const int lin  = blockIdx.x + (blockIdx.y << 4);
    const int lin2 = ((lin & 7) << 5) + (lin >> 3);
    const int n0 = (lin2 >> 4) * 64;
    const int m0 = (lin2 & 15) * 128;

    __shared__ u16 lA[6][128 * 32];
    __shared__ u16 lB[6][64 * 32];

    const int t = threadIdx.x, lane = t & 63, wave = t >> 6;
    const int wm = (wave >> 1) * 64, wn = (wave & 1) * 32;
    const int rl = lane & 15, kh = lane >> 4;

    fx4 acc[4][2];
    #pragma unroll
    for (int i = 0; i < 4; ++i)
        #pragma unroll
        for (int j = 0; j < 2; ++j) acc[i][j] = (fx4){0.f, 0.f, 0.f, 0.f};

    // staging: A 512 slots (2/thread), B 256 slots (1/thread); 16B slots
    // slot s -> row s>>2, chunk-pos s&3; src chunk = pos ^ ((row>>1)&3)
    const int sA0 = t, sA1 = t + 256, sB = t;
    const int rA0 = sA0 >> 2, cA0 = (sA0 & 3) ^ ((rA0 >> 1) & 3);
    const int rA1 = sA1 >> 2, cA1 = (sA1 & 3) ^ ((rA1 >> 1) & 3);
    const int rB  = sB  >> 2, cB  = (sB  & 3) ^ ((rB  >> 1) & 3);
    const u16* gA0 = A  + (size_t)(m0 + rA0) * K + cA0 * 8;
    const u16* gA1 = A  + (size_t)(m0 + rA1) * K + cA1 * 8;
    const u16* gB0 = BT + (size_t)(n0 + rB) * K + cB * 8;

    // frag read offsets: row r, k-chunk kh -> r*32 + ((kh ^ ((r>>1)&3))*8)
    int aoff[4], boff[2];
    #pragma unroll
    for (int f = 0; f < 4; ++f) {
        int ra = wm + f * 16 + rl;
        aoff[f] = ra * 32 + ((kh ^ ((ra >> 1) & 3)) * 8);
    }
    #pragma unroll
    for (int f = 0; f < 2; ++f) {
        int rb = wn + f * 16 + rl;
        boff[f] = rb * 32 + ((kh ^ ((rb >> 1) & 3)) * 8);
    }

#define STAGE(BF, K0) do { \
        gld16(gA0 + (K0), &lA[BF][sA0 * 8]); \
        gld16(gA1 + (K0), &lA[BF][sA1 * 8]); \
        gld16(gB0 + (K0), &lB[BF][sB  * 8]); } while (0)

    const int NT = K >> 5;   // >= 16 for all uses
    STAGE(0, 0); STAGE(1, 32); STAGE(2, 64);
    WAIT_VM(6); SBAR(); SFENCE();

    int bcur = 0, bpre = 3;
    for (int it = 0; it < NT; ++it) {
        if (it + 3 < NT) {
            STAGE(bpre, (it + 3) << 5);
            WAIT_VM(9);          // tile `it` complete; 3 newest tiles in flight
        } else if (it + 2 < NT) {
            WAIT_VM(6);
        } else if (it + 1 < NT) {
            WAIT_VM(3);
        } else {
            WAIT_VM(0);
        }
        SBAR(); SFENCE();
        const u16* bA = lA[bcur];
        const u16* bB = lB[bcur];
        bfx8 af[4], bfr[2];
        #pragma unroll
        for (int f = 0; f < 4; ++f) af[f] = *(const bfx8*)&bA[aoff[f]];
        #pragma unroll
        for (int f = 0; f < 2; ++f) bfr[f] = *(const bfx8*)&bB[boff[f]];
        __builtin_amdgcn_s_setprio(1);
        #pragma unroll
        for (int fm = 0; fm < 4; ++fm)
            #pragma unroll
            for (int fn = 0; fn < 2; ++fn)
                acc[fm][fn] = MFMA16(af[fm], bfr[fn], acc[fm][fn], 0, 0, 0);
        __builtin_amdgcn_s_setprio(0);
        if (++bcur == 6) bcur = 0;
        if (++bpre == 6) bpre = 0;
    }
#undef STAGE

    if (NA == 3 && which == 2) {
        // v: store normal orientation bf16 [b][M][N]
        u16* Vn = (u16*)Cb2 + (size_t)b * (size_t)M * N;
        #pragma unroll
        for (int fm = 0; fm < 4; ++fm) {
            int mg = m0 + wm + fm * 16 + kh * 4;
            #pragma unroll
            for (int fn = 0; fn < 2; ++fn) {
                int ng = n0 + wn + fn * 16 + rl;
                #pragma unroll
                for (int r = 0; r < 4; ++r)
                    Vn[(size_t)(mg + r) * N + ng] = f2b(acc[fm][fn][r] + bias[mg + r]);
            }
        }
    } else if (CT_OUT) {
        const float sc = (NA == 3 && which == 0) ? 0.125f : 1.0f;
        u16* CT = (u16*)Cb + (size_t)which * sWhich + (size_t)b * sC;
        #pragma unroll
        for (int fm = 0; fm < 4; ++fm) {
            int mg = m0 + wm + fm * 16 + kh * 4;
            float bi0 = bias[mg], bi1 = bias[mg + 1], bi2 = bias[mg + 2], bi3 = bias[mg + 3];
            #pragma unroll
            for (int fn = 0; fn < 2; ++fn) {
                int ng = n0 + wn + fn * 16 + rl;
                float v0 = (acc[fm][fn][0] + bi0) * sc;
                float v1 = (acc[fm][fn][1] + bi1) * sc;
                float v2 = (acc[fm][fn][2] + bi2) * sc;
                float v3 = (acc[fm][fn][3] + bi3) * sc;
                if (RELU) {
                    v0 = fmaxf(v0, 0.f); v1 = fmaxf(v1, 0.f);
                    v2 = fmaxf(v2, 0.f); v3 = fmaxf(v3, 0.f);
                }
                us4 o = { f2b(v0), f2b(v1), f2b(v2), f2b(v3) };
                *(us4*)(CT + (size_t)ng * M + mg) = o;
            }
        }
    } else {
        float* C = (float*)Cb + (size_t)b * sC;
        #pragma unroll
        for (int fm = 0; fm < 4; ++fm) {
            int mg = m0 + wm + fm * 16 + kh * 4;
            #pragma unroll
            for (int fn = 0; fn < 2; ++fn) {
                int ng = n0 + wn + fn * 16 + rl;
                #pragma unroll
                for (int r = 0; r < 4; ++r) {
                    float v = acc[fm][fn][r] + bias[mg + r];
                    if (RELU) v = fmaxf(v, 0.f);
                    C[(size_t)(mg + r) * N + ng] = v;
                }
            }
        }
    }
}

// ---------------------------------------------------------------------------
// Pass A: S[l] = sum_m exp(att[l,m] - |l-m|/8)  (q pre-scaled by 1/8; no max:
// |s| <= ~10 so fp32 exp is safe).  Block = 64 l-rows of one (b,h).
// grid (L/64, B*H).  Depth-2 prefetch on k-tiles.
// ---------------------------------------------------------------------------
__global__ __launch_bounds__(256) void attn_stats(
    const u16* __restrict__ qT, const u16* __restrict__ kT,
    float* __restrict__ rinv)
{
    const int lt = blockIdx.x;
    const int bh = blockIdx.y;
    const int b = bh >> 5, h = bh & 31;
    const size_t base = (size_t)b * L * AF + h * DH;

    __shared__ u16 lq[64 * 64];
    __shared__ u16 lk[4][64 * 64];
    __shared__ float sS[4][64];

    const int t = threadIdx.x, lane = t & 63, wave = t >> 6;
    const int rl = lane & 15, g = lane >> 4;

    // staging: 512 slots of 16B; slot -> row s>>3, chunk-pos s&7; src = pos ^ (r&7)
    const int s0 = t, s1 = t + 256;
    const int r0 = s0 >> 3, cs0 = (s0 & 7) ^ (r0 & 7);
    const int r1 = s1 >> 3, cs1 = (s1 & 7) ^ (r1 & 7);

    const u16* gk0 = kT + base + (size_t)r0 * AF + cs0 * 8;
    const u16* gk1 = kT + base + (size_t)r1 * AF + cs1 * 8;

    gld16(qT + base + (size_t)(lt * 64 + r0) * AF + cs0 * 8, lq + s0 * 8);
    gld16(qT + base + (size_t)(lt * 64 + r1) * AF + cs1 * 8, lq + s1 * 8);
    gld16(gk0, &lk[0][s0 * 8]);
    gld16(gk1, &lk[0][s1 * 8]);
    gld16(gk0 + (size_t)64 * AF, &lk[1][s0 * 8]);
    gld16(gk1 + (size_t)64 * AF, &lk[1][s1 * 8]);
    WAIT_VM(2); SBAR(); SFENCE();    // q + k0 landed

    const int rmr = wave * 16 + rl;
    const int akoff0 = rmr * 64 + ((g ^ (rmr & 7)) * 8);
    const int akoff1 = rmr * 64 + (((g + 4) ^ (rmr & 7)) * 8);
    bfx8 qf0[4], qf1[4];
    #pragma unroll
    for (int f = 0; f < 4; ++f) {
        int rq = f * 16 + rl;
        qf0[f] = *(const bfx8*)&lq[rq * 64 + ((g ^ (rq & 7)) * 8)];
        qf1[f] = *(const bfx8*)&lq[rq * 64 + (((g + 4) ^ (rq & 7)) * 8)];
    }

    float Sx[4] = {0.f, 0.f, 0.f, 0.f};
    for (int mt = 0; mt < 16; ++mt) {
        if (mt + 2 < 16) {
            const int bf = (mt + 2) & 3;
            gld16(gk0 + (size_t)(mt + 2) * 64 * AF, &lk[bf][s0 * 8]);
            gld16(gk1 + (size_t)(mt + 2) * 64 * AF, &lk[bf][s1 * 8]);
            WAIT_VM(4);
        } else if (mt + 1 < 16) {
            WAIT_VM(2);
        } else {
            WAIT_VM(0);
        }
        SBAR(); SFENCE();
        const u16* kb = lk[mt & 3];
        bfx8 ak0 = *(const bfx8*)&kb[akoff0];
        bfx8 ak1 = *(const bfx8*)&kb[akoff1];
        const float mb = (float)(mt * 64 + wave * 16 + g * 4);
        #pragma unroll
        for (int fn = 0; fn < 4; ++fn) {
            fx4 att = (fx4){0.f, 0.f, 0.f, 0.f};
            att = MFMA16(ak0, qf0[fn], att, 0, 0, 0);
            att = MFMA16(ak1, qf1[fn], att, 0, 0, 0);
            const float lgf = (float)(lt * 64 + fn * 16 + rl);
            float e0 = __expf(att[0] - 0.125f * fabsf(lgf - mb));
            float e1 = __expf(att[1] - 0.125f * fabsf(lgf - (mb + 1.f)));
            float e2 = __expf(att[2] - 0.125f * fabsf(lgf - (mb + 2.f)));
            float e3 = __expf(att[3] - 0.125f * fabsf(lgf - (mb + 3.f)));
            Sx[fn] += (e0 + e1) + (e2 + e3);
        }
    }
    #pragma unroll
    for (int fn = 0; fn < 4; ++fn) {
        float s_ = Sx[fn];
        s_ += __shfl_xor(s_, 16);
        s_ += __shfl_xor(s_, 32);
        if (lane < 16) sS[wave][fn * 16 + rl] = s_;
    }
    __syncthreads();
    if (t < 64) {
        float s_ = sS[0][t] + sS[1][t] + sS[2][t] + sS[3][t];
        rinv[(size_t)bh * L + lt * 64 + t] = 1.0f / s_;
    }
}

// ---------------------------------------------------------------------------
// Pass B: O[d,m] = sum_{l<=m} v[d,l] * exp(s[l,m]) * rinv[l]; h=relu(O) -> hT.
// Block = (b,h) x m-tile-pair (mt, 15-mt): 17 l-units each. grid (8, B*H).
// Double-buffered q/v prefetch; raw barriers (no vmcnt drain mid-iter).
// ---------------------------------------------------------------------------
__global__ __launch_bounds__(256) void attn_pv(
    const u16* __restrict__ qT, const u16* __restrict__ kT, const u16* __restrict__ v,
    const float* __restrict__ rinv, u16* __restrict__ hT)
{
    const int pair = blockIdx.x;
    const int bh = blockIdx.y;
    const int b = bh >> 5, h = bh & 31;
    const size_t qkbase = (size_t)b * L * AF + h * DH;
    const size_t vbase  = ((size_t)b * AF + h * DH) * L;
    const size_t rbase  = (size_t)bh * L;

    __shared__ u16 lkt[64 * 64];
    __shared__ u16 lqt[2][64 * 64], lv[2][64 * 64];
    __shared__ u16 lw[64 * 68];   // wT[m][l], pad 68

    const int t = threadIdx.x, lane = t & 63, wave = t >> 6;
    const int rl = lane & 15, g = lane >> 4;

    const int s0 = t, s1 = t + 256;
    const int r0 = s0 >> 3, cs0 = (s0 & 7) ^ (r0 & 7);
    const int r1 = s1 >> 3, cs1 = (s1 & 7) ^ (r1 & 7);

    const u16* gq0 = qT + qkbase + (size_t)r0 * AF + cs0 * 8;
    const u16* gq1 = qT + qkbase + (size_t)r1 * AF + cs1 * 8;
    const u16* gv0 = v + vbase + (size_t)r0 * L + cs0 * 8;
    const u16* gv1 = v + vbase + (size_t)r1 * L + cs1 * 8;

    const int rmr = wave * 16 + rl;     // phase-1 A rows (m), phase-2 A rows (d)
    const int toff0 = rmr * 64 + ((g ^ (rmr & 7)) * 8);
    const int toff1 = rmr * 64 + (((g + 4) ^ (rmr & 7)) * 8);
    int qoff0[4], qoff1[4];
    #pragma unroll
    for (int f = 0; f < 4; ++f) {
        int rq = f * 16 + rl;
        qoff0[f] = rq * 64 + ((g ^ (rq & 7)) * 8);
        qoff1[f] = rq * 64 + (((g + 4) ^ (rq & 7)) * 8);
    }

    for (int half = 0; half < 2; ++half) {
        const int mt = half ? pair : 15 - pair;
        const int m0 = mt * 64;

        // prologue: K-tile + first q/v tile (all prior vmem drained)
        gld16(kT + qkbase + (size_t)(m0 + r0) * AF + cs0 * 8, lkt + s0 * 8);
        gld16(kT + qkbase + (size_t)(m0 + r1) * AF + cs1 * 8, lkt + s1 * 8);
        gld16(gq0, &lqt[0][s0 * 8]);
        gld16(gq1, &lqt[0][s1 * 8]);
        gld16(gv0, &lv[0][s0 * 8]);
        gld16(gv1, &lv[0][s1 * 8]);
        WAIT_VM(0); SBAR(); SFENCE();

        fx4 oa[4];
        #pragma unroll
        for (int f = 0; f < 4; ++f) oa[f] = (fx4){0.f, 0.f, 0.f, 0.f};

        int cur = 0;
        for (int lt = 0; lt <= mt; ++lt) {
            if (lt < mt) {   // prefetch next q/v tile into the other buffer
                gld16(gq0 + (size_t)(lt + 1) * 64 * AF, &lqt[cur ^ 1][s0 * 8]);
                gld16(gq1 + (size_t)(lt + 1) * 64 * AF, &lqt[cur ^ 1][s1 * 8]);
                gld16(gv0 + (lt + 1) * 64, &lv[cur ^ 1][s0 * 8]);
                gld16(gv1 + (lt + 1) * 64, &lv[cur ^ 1][s1 * 8]);
            }
            // phase 1: att^T[m][l] = mfma(kT rows m, qT rows l) -> weights in lw
            bfx8 ak0 = *(const bfx8*)&lkt[toff0];
            bfx8 ak1 = *(const bfx8*)&lkt[toff1];
            const u16* qb = lqt[cur];
            #pragma unroll
            for (int fn = 0; fn < 4; ++fn) {
                bfx8 q0 = *(const bfx8*)&qb[qoff0[fn]];
                bfx8 q1 = *(const bfx8*)&qb[qoff1[fn]];
                fx4 att = (fx4){0.f, 0.f, 0.f, 0.f};
                att = MFMA16(ak0, q0, att, 0, 0, 0);
                att = MFMA16(ak1, q1, att, 0, 0, 0);
                const int lg = lt * 64 + fn * 16 + rl;
                float ri = rinv[rbase + lg];
                const float db = (float)(lg - (m0 + wave * 16 + g * 4));
                #pragma unroll
                for (int r = 0; r < 4; ++r) {
                    int mloc = wave * 16 + g * 4 + r;
                    float s = att[r] - 0.125f * fabsf(db - (float)r);
                    float w = (lg <= m0 + mloc) ? __expf(s) * ri : 0.f;
                    lw[mloc * 68 + fn * 16 + rl] = f2b(w);
                }
            }
            WAIT_LGKM0(); SBAR(); SFENCE();   // lw visible; prefetch stays in flight

            // phase 2: O[d][m] += mfma(v rows d, wT rows m)
            const u16* vb = lv[cur];
            bfx8 av0 = *(const bfx8*)&vb[toff0];
            bfx8 av1 = *(const bfx8*)&vb[toff1];
            #pragma unroll
            for (int fn = 0; fn < 4; ++fn) {
                const u16* wrow = &lw[(fn * 16 + rl) * 68];
                union { bfx8 f; bfx4 hh[2]; } w0, w1;
                w0.hh[0] = *(const bfx4*)&wrow[g * 8];
                w0.hh[1] = *(const bfx4*)&wrow[g * 8 + 4];
                w1.hh[0] = *(const bfx4*)&wrow[(g + 4) * 8];
                w1.hh[1] = *(const bfx4*)&wrow[(g + 4) * 8 + 4];
                oa[fn] = MFMA16(av0, w0.f, oa[fn], 0, 0, 0);
                oa[fn] = MFMA16(av1, w1.f, oa[fn], 0, 0, 0);
            }
            WAIT_VM(0); WAIT_LGKM0(); SBAR(); SFENCE();   // next tile landed; reads done
            cur ^= 1;
        }

        // epilogue: relu, C^T store -> hT[b][m][h*64+d]
        #pragma unroll
        for (int fn = 0; fn < 4; ++fn) {
            int mg = m0 + fn * 16 + rl;
            int cg = h * DH + wave * 16 + g * 4;
            us4 o = { f2b(fmaxf(oa[fn][0], 0.f)), f2b(fmaxf(oa[fn][1], 0.f)),
                      f2b(fmaxf(oa[fn][2], 0.f)), f2b(fmaxf(oa[fn][3], 0.f)) };
            *(us4*)(hT + ((size_t)b * L + mg) * AF + cg) = o;
        }
    }
}

// ---------------------------------------------------------------------------
extern "C" void kernel_launch(void* const* d_in, const int* in_sizes, int n_in,
                              void* d_out, int out_size, void* d_ws, size_t ws_size,
                              hipStream_t stream)
{
    (void)in_sizes; (void)n_in; (void)out_size; (void)ws_size;
    const float* x  = (const float*)d_in[0];
    const float* Wq = (const float*)d_in[1];
    const float* bq = (const float*)d_in[2];
    const float* Wk = (const float*)d_in[3];
    const float* bk = (const float*)d_in[4];
    const float* Wv = (const float*)d_in[5];
    const float* bv = (const float*)d_in[6];
    const float* W1 = (const float*)d_in[7];
    const float* b1 = (const float*)d_in[8];
    const float* W2 = (const float*)d_in[9];
    const float* b2 = (const float*)d_in[10];

    u16* wsp = (u16*)d_ws;
    size_t o = 0;
    u16* xT  = wsp + o; o += (size_t)NB * L * CIN;
    u16* qT  = wsp + o; o += (size_t)NB * L * AF;   // q (pre-scaled by 1/8), [b][l][af]
    u16* kT  = wsp + o; o += (size_t)NB * L * AF;   // must follow qT (which*sWhich)
    u16* vdm = wsp + o; o += (size_t)NB * AF * L;   // v normal orientation [b][af][l]
    u16* hT  = wsp + o; o += (size_t)NB * L * AF;
    u16* z1T = wsp + o; o += (size_t)NB * L * AF;
    u16* Wqb = wsp + o; o += (size_t)AF * CIN;
    u16* Wkb = wsp + o; o += (size_t)AF * CIN;
    u16* Wvb = wsp + o; o += (size_t)AF * CIN;
    u16* W1b = wsp + o; o += (size_t)AF * AF;
    u16* W2b = wsp + o; o += (size_t)AF * AF;
    float* rinv = (float*)(wsp + o); o += (size_t)NB * NH * L * 2;

    dim3 blk(256);

    convert_xT<<<dim3(CIN / 64, L / 64, NB), blk, 0, stream>>>(x, xT);
    convert_f2b_multi<<<dim3(256, 1, 3), blk, 0, stream>>>(Wq, Wk, Wv, Wqb, Wkb, Wvb, AF * CIN / 4);
    convert_f2b_multi<<<dim3(1024, 1, 2), blk, 0, stream>>>(W1, W2, W2, W1b, W2b, W2b, AF * AF / 4);

    // QKV: qT/kT = (W? * x)^T (q scaled 1/8); v -> vdm normal orientation
    gemm_bt<0, 1, 3><<<dim3(16, 16, NB * 3), blk, 0, stream>>>(
        Wqb, Wkb, Wvb, bq, bk, bv, xT, qT, vdm,
        AF, L, CIN, (size_t)L * CIN, (size_t)L * AF, (size_t)NB * L * AF);

    attn_stats<<<dim3(L / 64, NB * NH), blk, 0, stream>>>(qT, kT, rinv);
    attn_pv<<<dim3(8, NB * NH), blk, 0, stream>>>(qT, kT, vdm, rinv, hT);

    // z1T = relu(W1*h + b1)^T
    gemm_bt<1, 1, 1><<<dim3(16, 16, NB), blk, 0, stream>>>(
        W1b, nullptr, nullptr, b1, nullptr, nullptr, hT, z1T, nullptr,
        AF, L, AF, (size_t)L * AF, (size_t)L * AF, 0);
    // out = W2*z1 + b2 (fp32, normal orientation)
    gemm_bt<0, 0, 1><<<dim3(16, 16, NB), blk, 0, stream>>>(
        W2b, nullptr, nullptr, b2, nullptr, nullptr, z1T, d_out, nullptr,
        AF, L, AF, (size_t)L * AF, (size_t)AF * L, 0);
}

// Round 6
// 146.846 us; speedup vs baseline: 1.5271x; 1.2369x over previous
//
#include <hip/hip_runtime.h>

#define L 1024
#define CIN 512
#define NH 32
#define DH 64
#define NB 2
#define AF 2048

typedef unsigned short u16;
typedef unsigned int u32;
typedef __attribute__((ext_vector_type(8))) short bfx8;   // 8 bf16 = 4 VGPR (MFMA A/B frag)
typedef __attribute__((ext_vector_type(4))) short bfx4;   // 8B half-frag
typedef __attribute__((ext_vector_type(4))) float fx4;    // MFMA C/D frag

struct __align__(8) us4 { u16 x, y, z, w; };

#define MFMA16 __builtin_amdgcn_mfma_f32_16x16x32_bf16
#define SBAR() __builtin_amdgcn_s_barrier()
#define SFENCE() __builtin_amdgcn_sched_barrier(0)
#define WAIT_VM(N) asm volatile("s_waitcnt vmcnt(" #N ")" ::: "memory")
#define WAIT_LGKM0() asm volatile("s_waitcnt lgkmcnt(0)" ::: "memory")

__device__ inline void gld16(const void* g, void* l) {
    __builtin_amdgcn_global_load_lds(
        (const __attribute__((address_space(1))) u32*)g,
        (__attribute__((address_space(3))) u32*)l, 16, 0, 0);
}

__device__ inline u16 f2b(float f) {
    union { float f; u32 u; } v; v.f = f;
    u32 u = v.u;
    return (u16)((u + 0x7fffu + ((u >> 16) & 1u)) >> 16);
}

// ---------------------------------------------------------------------------
// prep: all fp32->bf16 weight converts (z=0..4) + x transpose/convert (z=5).
// grid (512, 1, 6), block 256.
// ---------------------------------------------------------------------------
__global__ __launch_bounds__(256) void prep(
    const float* __restrict__ x,
    const float* __restrict__ Wq, const float* __restrict__ Wk, const float* __restrict__ Wv,
    const float* __restrict__ W1, const float* __restrict__ W2,
    u16* __restrict__ xT, u16* __restrict__ Wqb, u16* __restrict__ Wkb,
    u16* __restrict__ Wvb, u16* __restrict__ W1b, u16* __restrict__ W2b)
{
    __shared__ u16 tile[64][68];
    const int z = blockIdx.z;
    const int t = threadIdx.x;
    if (z < 5) {
        const float* in; u16* out; int n4;
        switch (z) {
            case 0: in = Wq; out = Wqb; n4 = AF * CIN / 4; break;
            case 1: in = Wk; out = Wkb; n4 = AF * CIN / 4; break;
            case 2: in = Wv; out = Wvb; n4 = AF * CIN / 4; break;
            case 3: in = W1; out = W1b; n4 = AF * AF / 4; break;
            default: in = W2; out = W2b; n4 = AF * AF / 4; break;
        }
        int i = blockIdx.x * 256 + t;
        for (; i < n4; i += 512 * 256) {
            float4 v = ((const float4*)in)[i];
            us4 o = { f2b(v.x), f2b(v.y), f2b(v.z), f2b(v.w) };
            ((us4*)out)[i] = o;
        }
    } else {
        const int bid = blockIdx.x;
        if (bid >= 256) return;
        const int c0 = (bid & 7) * 64, l0 = ((bid >> 3) & 15) * 64, b = bid >> 7;
        const int tr = t >> 4, tc4 = (t & 15) * 4;
        #pragma unroll
        for (int p = 0; p < 4; ++p) {
            int c = p * 16 + tr;
            float4 v = *(const float4*)(x + ((size_t)(b * CIN + c0 + c)) * L + l0 + tc4);
            tile[c][tc4 + 0] = f2b(v.x); tile[c][tc4 + 1] = f2b(v.y);
            tile[c][tc4 + 2] = f2b(v.z); tile[c][tc4 + 3] = f2b(v.w);
        }
        __syncthreads();
        #pragma unroll
        for (int p = 0; p < 4; ++p) {
            int l = p * 16 + tr;
            us4 o = { tile[tc4 + 0][l], tile[tc4 + 1][l], tile[tc4 + 2][l], tile[tc4 + 3][l] };
            *(us4*)(xT + ((size_t)(b * L + l0 + l)) * CIN + c0 + tc4) = o;
        }
    }
}

// ---------------------------------------------------------------------------
// MFMA GEMM, depth-3 counted-vmcnt pipeline (6 LDS buffers, 1 barrier/K-step).
// C[M,N] = A[M,K] * B[K,N] (+bias[M], opt relu). A row-major, BT=[N][K].
// Tile 128(M) x 64(N), BK=32, 256 threads = 4 waves (2x2, wave-tile 64x32).
// Grid is ALWAYS (16,16,z): requires M=2048, N=1024. XCD-contiguous remap.
// CT_OUT=1: store C^T bf16 [N][M].  CT_OUT=0: store C fp32 [M][N].
// NA=3 (QKV): grid.z = b*3+which; which==0 scales output by 0.125 (q/sqrt(D));
//             which==2 stores NORMAL orientation bf16 [b][M][N] into Cb2.
// ---------------------------------------------------------------------------
template<int RELU, int CT_OUT, int NA>
__global__ __launch_bounds__(256) void gemm_bt(
    const u16* __restrict__ A0, const u16* __restrict__ A1, const u16* __restrict__ A2,
    const float* __restrict__ bias0, const float* __restrict__ bias1, const float* __restrict__ bias2,
    const u16* __restrict__ BTb, void* __restrict__ Cb, void* __restrict__ Cb2,
    int M, int N, int K, size_t sBT, size_t sC, size_t sWhich)
{
    const int z = blockIdx.z;
    const int which = (NA == 3) ? (z % 3) : 0;
    const int b     = (NA == 3) ? (z / 3) : z;
    const u16* __restrict__ A = (which == 0) ? A0 : (which == 1) ? A1 : A2;
    const float* __restrict__ bias = (which == 0) ? bias0 : (which == 1) ? bias1 : bias2;
    const u16* __restrict__ BT = BTb + (size_t)b * sBT;

    // XCD-contiguous tile remap: XCD k (= lin%8) owns 2 N-columns x all 16 M-tiles
    const int lin  = blockIdx.x + (blockIdx.y << 4);
    const int lin2 = ((lin & 7) << 5) + (lin >> 3);
    const int n0 = (lin2 >> 4) * 64;
    const int m0 = (lin2 & 15) * 128;

    __shared__ u16 lA[6][128 * 32];
    __shared__ u16 lB[6][64 * 32];

    const int t = threadIdx.x, lane = t & 63, wave = t >> 6;
    const int wm = (wave >> 1) * 64, wn = (wave & 1) * 32;
    const int rl = lane & 15, kh = lane >> 4;

    fx4 acc[4][2];
    #pragma unroll
    for (int i = 0; i < 4; ++i)
        #pragma unroll
        for (int j = 0; j < 2; ++j) acc[i][j] = (fx4){0.f, 0.f, 0.f, 0.f};

    // staging: A 512 slots (2/thread), B 256 slots (1/thread); 16B slots
    // slot s -> row s>>2, chunk-pos s&3; src chunk = pos ^ ((row>>1)&3)
    const int sA0 = t, sA1 = t + 256, sB = t;
    const int rA0 = sA0 >> 2, cA0 = (sA0 & 3) ^ ((rA0 >> 1) & 3);
    const int rA1 = sA1 >> 2, cA1 = (sA1 & 3) ^ ((rA1 >> 1) & 3);
    const int rB  = sB  >> 2, cB  = (sB  & 3) ^ ((rB  >> 1) & 3);
    const u16* gA0 = A  + (size_t)(m0 + rA0) * K + cA0 * 8;
    const u16* gA1 = A  + (size_t)(m0 + rA1) * K + cA1 * 8;
    const u16* gB0 = BT + (size_t)(n0 + rB) * K + cB * 8;

    // frag read offsets: row r, k-chunk kh -> r*32 + ((kh ^ ((r>>1)&3))*8)
    int aoff[4], boff[2];
    #pragma unroll
    for (int f = 0; f < 4; ++f) {
        int ra = wm + f * 16 + rl;
        aoff[f] = ra * 32 + ((kh ^ ((ra >> 1) & 3)) * 8);
    }
    #pragma unroll
    for (int f = 0; f < 2; ++f) {
        int rb = wn + f * 16 + rl;
        boff[f] = rb * 32 + ((kh ^ ((rb >> 1) & 3)) * 8);
    }

#define STAGE(BF, K0) do { \
        gld16(gA0 + (K0), &lA[BF][sA0 * 8]); \
        gld16(gA1 + (K0), &lA[BF][sA1 * 8]); \
        gld16(gB0 + (K0), &lB[BF][sB  * 8]); } while (0)

    const int NT = K >> 5;   // >= 16 for all uses
    STAGE(0, 0); STAGE(1, 32); STAGE(2, 64);
    WAIT_VM(6); SBAR(); SFENCE();

    int bcur = 0, bpre = 3;
    for (int it = 0; it < NT; ++it) {
        if (it + 3 < NT) {
            STAGE(bpre, (it + 3) << 5);
            WAIT_VM(9);          // tile `it` complete; 3 newest tiles in flight
        } else if (it + 2 < NT) {
            WAIT_VM(6);
        } else if (it + 1 < NT) {
            WAIT_VM(3);
        } else {
            WAIT_VM(0);
        }
        SBAR(); SFENCE();
        const u16* bA = lA[bcur];
        const u16* bB = lB[bcur];
        bfx8 af[4], bfr[2];
        #pragma unroll
        for (int f = 0; f < 4; ++f) af[f] = *(const bfx8*)&bA[aoff[f]];
        #pragma unroll
        for (int f = 0; f < 2; ++f) bfr[f] = *(const bfx8*)&bB[boff[f]];
        __builtin_amdgcn_s_setprio(1);
        #pragma unroll
        for (int fm = 0; fm < 4; ++fm)
            #pragma unroll
            for (int fn = 0; fn < 2; ++fn)
                acc[fm][fn] = MFMA16(af[fm], bfr[fn], acc[fm][fn], 0, 0, 0);
        __builtin_amdgcn_s_setprio(0);
        if (++bcur == 6) bcur = 0;
        if (++bpre == 6) bpre = 0;
    }
#undef STAGE

    if (NA == 3 && which == 2) {
        // v: store normal orientation bf16 [b][M][N]
        u16* Vn = (u16*)Cb2 + (size_t)b * (size_t)M * N;
        #pragma unroll
        for (int fm = 0; fm < 4; ++fm) {
            int mg = m0 + wm + fm * 16 + kh * 4;
            #pragma unroll
            for (int fn = 0; fn < 2; ++fn) {
                int ng = n0 + wn + fn * 16 + rl;
                #pragma unroll
                for (int r = 0; r < 4; ++r)
                    Vn[(size_t)(mg + r) * N + ng] = f2b(acc[fm][fn][r] + bias[mg + r]);
            }
        }
    } else if (CT_OUT) {
        const float sc = (NA == 3 && which == 0) ? 0.125f : 1.0f;
        u16* CT = (u16*)Cb + (size_t)which * sWhich + (size_t)b * sC;
        #pragma unroll
        for (int fm = 0; fm < 4; ++fm) {
            int mg = m0 + wm + fm * 16 + kh * 4;
            float bi0 = bias[mg], bi1 = bias[mg + 1], bi2 = bias[mg + 2], bi3 = bias[mg + 3];
            #pragma unroll
            for (int fn = 0; fn < 2; ++fn) {
                int ng = n0 + wn + fn * 16 + rl;
                float v0 = (acc[fm][fn][0] + bi0) * sc;
                float v1 = (acc[fm][fn][1] + bi1) * sc;
                float v2 = (acc[fm][fn][2] + bi2) * sc;
                float v3 = (acc[fm][fn][3] + bi3) * sc;
                if (RELU) {
                    v0 = fmaxf(v0, 0.f); v1 = fmaxf(v1, 0.f);
                    v2 = fmaxf(v2, 0.f); v3 = fmaxf(v3, 0.f);
                }
                us4 o = { f2b(v0), f2b(v1), f2b(v2), f2b(v3) };
                *(us4*)(CT + (size_t)ng * M + mg) = o;
            }
        }
    } else {
        float* C = (float*)Cb + (size_t)b * sC;
        #pragma unroll
        for (int fm = 0; fm < 4; ++fm) {
            int mg = m0 + wm + fm * 16 + kh * 4;
            #pragma unroll
            for (int fn = 0; fn < 2; ++fn) {
                int ng = n0 + wn + fn * 16 + rl;
                #pragma unroll
                for (int r = 0; r < 4; ++r) {
                    float v = acc[fm][fn][r] + bias[mg + r];
                    if (RELU) v = fmaxf(v, 0.f);
                    C[(size_t)(mg + r) * N + ng] = v;
                }
            }
        }
    }
}

// ---------------------------------------------------------------------------
// Pass A (BANDED): S[l] = sum_{|m-l| <= ~128} exp(att[l,m] - |l-m|/8).
// Terms beyond the +-2-tile band are < e^-16 relative -- negligible vs bf16
// noise. Block = 64 l-rows of one (b,h); m-tiles in [lt-2, lt+2] (>=3 tiles).
// grid (16, B*H). Depth-2 prefetch preserved.
// ---------------------------------------------------------------------------
__global__ __launch_bounds__(256) void attn_stats(
    const u16* __restrict__ qT, const u16* __restrict__ kT,
    float* __restrict__ rinv)
{
    const int lt = blockIdx.x;
    const int bh = blockIdx.y;
    const int b = bh >> 5, h = bh & 31;
    const size_t base = (size_t)b * L * AF + h * DH;

    const int mlo = lt < 2 ? 0 : lt - 2;
    const int mhi = lt > 13 ? 15 : lt + 2;
    const int NTW = mhi - mlo + 1;   // 3..5 always

    __shared__ u16 lq[64 * 64];
    __shared__ u16 lk[4][64 * 64];
    __shared__ float sS[4][64];

    const int t = threadIdx.x, lane = t & 63, wave = t >> 6;
    const int rl = lane & 15, g = lane >> 4;

    // staging: 512 slots of 16B; slot -> row s>>3, chunk-pos s&7; src = pos ^ (r&7)
    const int s0 = t, s1 = t + 256;
    const int r0 = s0 >> 3, cs0 = (s0 & 7) ^ (r0 & 7);
    const int r1 = s1 >> 3, cs1 = (s1 & 7) ^ (r1 & 7);

    const u16* gk0 = kT + base + (size_t)(mlo * 64 + r0) * AF + cs0 * 8;
    const u16* gk1 = kT + base + (size_t)(mlo * 64 + r1) * AF + cs1 * 8;

    gld16(qT + base + (size_t)(lt * 64 + r0) * AF + cs0 * 8, lq + s0 * 8);
    gld16(qT + base + (size_t)(lt * 64 + r1) * AF + cs1 * 8, lq + s1 * 8);
    gld16(gk0, &lk[0][s0 * 8]);
    gld16(gk1, &lk[0][s1 * 8]);
    gld16(gk0 + (size_t)64 * AF, &lk[1][s0 * 8]);
    gld16(gk1 + (size_t)64 * AF, &lk[1][s1 * 8]);
    WAIT_VM(2); SBAR(); SFENCE();    // q + k0 landed

    const int rmr = wave * 16 + rl;
    const int akoff0 = rmr * 64 + ((g ^ (rmr & 7)) * 8);
    const int akoff1 = rmr * 64 + (((g + 4) ^ (rmr & 7)) * 8);
    bfx8 qf0[4], qf1[4];
    #pragma unroll
    for (int f = 0; f < 4; ++f) {
        int rq = f * 16 + rl;
        qf0[f] = *(const bfx8*)&lq[rq * 64 + ((g ^ (rq & 7)) * 8)];
        qf1[f] = *(const bfx8*)&lq[rq * 64 + (((g + 4) ^ (rq & 7)) * 8)];
    }

    float Sx[4] = {0.f, 0.f, 0.f, 0.f};
    for (int i = 0; i < NTW; ++i) {
        if (i + 2 < NTW) {
            const int bf = (i + 2) & 3;
            gld16(gk0 + (size_t)(i + 2) * 64 * AF, &lk[bf][s0 * 8]);
            gld16(gk1 + (size_t)(i + 2) * 64 * AF, &lk[bf][s1 * 8]);
            WAIT_VM(4);
        } else if (i + 1 < NTW) {
            WAIT_VM(2);
        } else {
            WAIT_VM(0);
        }
        SBAR(); SFENCE();
        const u16* kb = lk[i & 3];
        bfx8 ak0 = *(const bfx8*)&kb[akoff0];
        bfx8 ak1 = *(const bfx8*)&kb[akoff1];
        const float mb = (float)((mlo + i) * 64 + wave * 16 + g * 4);
        #pragma unroll
        for (int fn = 0; fn < 4; ++fn) {
            fx4 att = (fx4){0.f, 0.f, 0.f, 0.f};
            att = MFMA16(ak0, qf0[fn], att, 0, 0, 0);
            att = MFMA16(ak1, qf1[fn], att, 0, 0, 0);
            const float lgf = (float)(lt * 64 + fn * 16 + rl);
            float e0 = __expf(att[0] - 0.125f * fabsf(lgf - mb));
            float e1 = __expf(att[1] - 0.125f * fabsf(lgf - (mb + 1.f)));
            float e2 = __expf(att[2] - 0.125f * fabsf(lgf - (mb + 2.f)));
            float e3 = __expf(att[3] - 0.125f * fabsf(lgf - (mb + 3.f)));
            Sx[fn] += (e0 + e1) + (e2 + e3);
        }
    }
    #pragma unroll
    for (int fn = 0; fn < 4; ++fn) {
        float s_ = Sx[fn];
        s_ += __shfl_xor(s_, 16);
        s_ += __shfl_xor(s_, 32);
        if (lane < 16) sS[wave][fn * 16 + rl] = s_;
    }
    __syncthreads();
    if (t < 64) {
        float s_ = sS[0][t] + sS[1][t] + sS[2][t] + sS[3][t];
        rinv[(size_t)bh * L + lt * 64 + t] = 1.0f / s_;
    }
}

// ---------------------------------------------------------------------------
// Pass B (BANDED): O[d,m] = sum_{max(0,m-128-63) <= l <= m} v[d,l]*w[l,m];
// h = relu(O) -> hT[b][m][h*64+d].  Block = one (b,h, m-tile); l-tiles in
// [mt-2, mt].  grid (16, B*H) = 1024 blocks (4/CU).
// ---------------------------------------------------------------------------
__global__ __launch_bounds__(256) void attn_pv(
    const u16* __restrict__ qT, const u16* __restrict__ kT, const u16* __restrict__ v,
    const float* __restrict__ rinv, u16* __restrict__ hT)
{
    const int mt = blockIdx.x;
    const int bh = blockIdx.y;
    const int b = bh >> 5, h = bh & 31;
    const size_t qkbase = (size_t)b * L * AF + h * DH;
    const size_t vbase  = ((size_t)b * AF + h * DH) * L;
    const size_t rbase  = (size_t)bh * L;

    const int ltlo = mt < 2 ? 0 : mt - 2;
    const int NI = mt - ltlo + 1;    // 1..3
    const int m0 = mt * 64;

    __shared__ u16 lkt[64 * 64];
    __shared__ u16 lqt[2][64 * 64], lv[2][64 * 64];
    __shared__ u16 lw[64 * 68];   // wT[m][l], pad 68

    const int t = threadIdx.x, lane = t & 63, wave = t >> 6;
    const int rl = lane & 15, g = lane >> 4;

    const int s0 = t, s1 = t + 256;
    const int r0 = s0 >> 3, cs0 = (s0 & 7) ^ (r0 & 7);
    const int r1 = s1 >> 3, cs1 = (s1 & 7) ^ (r1 & 7);

    const u16* gq0 = qT + qkbase + (size_t)(ltlo * 64 + r0) * AF + cs0 * 8;
    const u16* gq1 = qT + qkbase + (size_t)(ltlo * 64 + r1) * AF + cs1 * 8;
    const u16* gv0 = v + vbase + ltlo * 64 + (size_t)r0 * L + cs0 * 8;
    const u16* gv1 = v + vbase + ltlo * 64 + (size_t)r1 * L + cs1 * 8;

    const int rmr = wave * 16 + rl;     // phase-1 A rows (m), phase-2 A rows (d)
    const int toff0 = rmr * 64 + ((g ^ (rmr & 7)) * 8);
    const int toff1 = rmr * 64 + (((g + 4) ^ (rmr & 7)) * 8);
    int qoff0[4], qoff1[4];
    #pragma unroll
    for (int f = 0; f < 4; ++f) {
        int rq = f * 16 + rl;
        qoff0[f] = rq * 64 + ((g ^ (rq & 7)) * 8);
        qoff1[f] = rq * 64 + (((g + 4) ^ (rq & 7)) * 8);
    }

    // prologue: K-tile + first q/v tile
    gld16(kT + qkbase + (size_t)(m0 + r0) * AF + cs0 * 8, lkt + s0 * 8);
    gld16(kT + qkbase + (size_t)(m0 + r1) * AF + cs1 * 8, lkt + s1 * 8);
    gld16(gq0, &lqt[0][s0 * 8]);
    gld16(gq1, &lqt[0][s1 * 8]);
    gld16(gv0, &lv[0][s0 * 8]);
    gld16(gv1, &lv[0][s1 * 8]);
    WAIT_VM(0); SBAR(); SFENCE();

    fx4 oa[4];
    #pragma unroll
    for (int f = 0; f < 4; ++f) oa[f] = (fx4){0.f, 0.f, 0.f, 0.f};

    int cur = 0;
    for (int i = 0; i < NI; ++i) {
        const int lt = ltlo + i;
        if (i + 1 < NI) {   // prefetch next q/v tile into the other buffer
            gld16(gq0 + (size_t)(i + 1) * 64 * AF, &lqt[cur ^ 1][s0 * 8]);
            gld16(gq1 + (size_t)(i + 1) * 64 * AF, &lqt[cur ^ 1][s1 * 8]);
            gld16(gv0 + (i + 1) * 64, &lv[cur ^ 1][s0 * 8]);
            gld16(gv1 + (i + 1) * 64, &lv[cur ^ 1][s1 * 8]);
        }
        // phase 1: att^T[m][l] = mfma(kT rows m, qT rows l) -> weights in lw
        bfx8 ak0 = *(const bfx8*)&lkt[toff0];
        bfx8 ak1 = *(const bfx8*)&lkt[toff1];
        const u16* qb = lqt[cur];
        #pragma unroll
        for (int fn = 0; fn < 4; ++fn) {
            bfx8 q0 = *(const bfx8*)&qb[qoff0[fn]];
            bfx8 q1 = *(const bfx8*)&qb[qoff1[fn]];
            fx4 att = (fx4){0.f, 0.f, 0.f, 0.f};
            att = MFMA16(ak0, q0, att, 0, 0, 0);
            att = MFMA16(ak1, q1, att, 0, 0, 0);
            const int lg = lt * 64 + fn * 16 + rl;
            float ri = rinv[rbase + lg];
            const float db = (float)(lg - (m0 + wave * 16 + g * 4));
            #pragma unroll
            for (int r = 0; r < 4; ++r) {
                int mloc = wave * 16 + g * 4 + r;
                float s = att[r] - 0.125f * fabsf(db - (float)r);
                float w = (lg <= m0 + mloc) ? __expf(s) * ri : 0.f;
                lw[mloc * 68 + fn * 16 + rl] = f2b(w);
            }
        }
        WAIT_LGKM0(); SBAR(); SFENCE();   // lw visible; prefetch stays in flight

        // phase 2: O[d][m] += mfma(v rows d, wT rows m)
        const u16* vb = lv[cur];
        bfx8 av0 = *(const bfx8*)&vb[toff0];
        bfx8 av1 = *(const bfx8*)&vb[toff1];
        #pragma unroll
        for (int fn = 0; fn < 4; ++fn) {
            const u16* wrow = &lw[(fn * 16 + rl) * 68];
            union { bfx8 f; bfx4 hh[2]; } w0, w1;
            w0.hh[0] = *(const bfx4*)&wrow[g * 8];
            w0.hh[1] = *(const bfx4*)&wrow[g * 8 + 4];
            w1.hh[0] = *(const bfx4*)&wrow[(g + 4) * 8];
            w1.hh[1] = *(const bfx4*)&wrow[(g + 4) * 8 + 4];
            oa[fn] = MFMA16(av0, w0.f, oa[fn], 0, 0, 0);
            oa[fn] = MFMA16(av1, w1.f, oa[fn], 0, 0, 0);
        }
        WAIT_VM(0); WAIT_LGKM0(); SBAR(); SFENCE();   // next tile landed; reads done
        cur ^= 1;
    }

    // epilogue: relu, C^T store -> hT[b][m][h*64+d]
    #pragma unroll
    for (int fn = 0; fn < 4; ++fn) {
        int mg = m0 + fn * 16 + rl;
        int cg = h * DH + wave * 16 + g * 4;
        us4 o = { f2b(fmaxf(oa[fn][0], 0.f)), f2b(fmaxf(oa[fn][1], 0.f)),
                  f2b(fmaxf(oa[fn][2], 0.f)), f2b(fmaxf(oa[fn][3], 0.f)) };
        *(us4*)(hT + ((size_t)b * L + mg) * AF + cg) = o;
    }
}

// ---------------------------------------------------------------------------
extern "C" void kernel_launch(void* const* d_in, const int* in_sizes, int n_in,
                              void* d_out, int out_size, void* d_ws, size_t ws_size,
                              hipStream_t stream)
{
    (void)in_sizes; (void)n_in; (void)out_size; (void)ws_size;
    const float* x  = (const float*)d_in[0];
    const float* Wq = (const float*)d_in[1];
    const float* bq = (const float*)d_in[2];
    const float* Wk = (const float*)d_in[3];
    const float* bk = (const float*)d_in[4];
    const float* Wv = (const float*)d_in[5];
    const float* bv = (const float*)d_in[6];
    const float* W1 = (const float*)d_in[7];
    const float* b1 = (const float*)d_in[8];
    const float* W2 = (const float*)d_in[9];
    const float* b2 = (const float*)d_in[10];

    u16* wsp = (u16*)d_ws;
    size_t o = 0;
    u16* xT  = wsp + o; o += (size_t)NB * L * CIN;
    u16* qT  = wsp + o; o += (size_t)NB * L * AF;   // q (pre-scaled by 1/8), [b][l][af]
    u16* kT  = wsp + o; o += (size_t)NB * L * AF;   // must follow qT (which*sWhich)
    u16* vdm = wsp + o; o += (size_t)NB * AF * L;   // v normal orientation [b][af][l]
    u16* hT  = wsp + o; o += (size_t)NB * L * AF;
    u16* z1T = wsp + o; o += (size_t)NB * L * AF;
    u16* Wqb = wsp + o; o += (size_t)AF * CIN;
    u16* Wkb = wsp + o; o += (size_t)AF * CIN;
    u16* Wvb = wsp + o; o += (size_t)AF * CIN;
    u16* W1b = wsp + o; o += (size_t)AF * AF;
    u16* W2b = wsp + o; o += (size_t)AF * AF;
    float* rinv = (float*)(wsp + o); o += (size_t)NB * NH * L * 2;

    dim3 blk(256);

    prep<<<dim3(512, 1, 6), blk, 0, stream>>>(x, Wq, Wk, Wv, W1, W2,
                                              xT, Wqb, Wkb, Wvb, W1b, W2b);

    // QKV: qT/kT = (W? * x)^T (q scaled 1/8); v -> vdm normal orientation
    gemm_bt<0, 1, 3><<<dim3(16, 16, NB * 3), blk, 0, stream>>>(
        Wqb, Wkb, Wvb, bq, bk, bv, xT, qT, vdm,
        AF, L, CIN, (size_t)L * CIN, (size_t)L * AF, (size_t)NB * L * AF);

    attn_stats<<<dim3(16, NB * NH), blk, 0, stream>>>(qT, kT, rinv);
    attn_pv<<<dim3(16, NB * NH), blk, 0, stream>>>(qT, kT, vdm, rinv, hT);

    // z1T = relu(W1*h + b1)^T
    gemm_bt<1, 1, 1><<<dim3(16, 16, NB), blk, 0, stream>>>(
        W1b, nullptr, nullptr, b1, nullptr, nullptr, hT, z1T, nullptr,
        AF, L, AF, (size_t)L * AF, (size_t)L * AF, 0);
    // out = W2*z1 + b2 (fp32, normal orientation)
    gemm_bt<0, 0, 1><<<dim3(16, 16, NB), blk, 0, stream>>>(
        W2b, nullptr, nullptr, b2, nullptr, nullptr, z1T, d_out, nullptr,
        AF, L, AF, (size_t)L * AF, (size_t)AF * L, 0);
}